// Round 2
// baseline (640.576 us; speedup 1.0000x reference)
//
#include <hip/hip_runtime.h>

typedef __bf16 bf16;
typedef __bf16 bf16x4 __attribute__((ext_vector_type(4)));
typedef __bf16 bf16x8 __attribute__((ext_vector_type(8)));
typedef float floatx4 __attribute__((ext_vector_type(4)));

#define MFMA(a, b, c) __builtin_amdgcn_mfma_f32_16x16x32_bf16((a), (b), (c), 0, 0, 0)

// Problem constants
constexpr int S = 35;        // 1 cls + 24 dims + 10 mem
constexpr int NH = 8;
constexpr int NL = 3;
constexpr int G = 2;         // batch items per block
constexpr int RP = 80;       // padded rows (G*35 = 70 -> 5 m-tiles)
constexpr int MT = 5;        // MFMA m-tiles
constexpr int XS = 72;       // x/attn LDS stride (bf16 elems; 144B rows -> 2-way banks, free)
constexpr int QS = 200;      // qkv LDS stride (400B rows, 16B-aligned)
constexpr int HS = 136;      // ff-chunk LDS stride
constexpr int SEQOFF = 4096 * 128;                 // 524288
constexpr int MEMOFF = SEQOFF + 4096 * 24 * 64;    // 6815744

struct Params {
    const int* tok;
    // fp32 inputs
    const float *traits, *relg, *mem, *temb, *demb, *traitW, *traitb, *intentW, *intentb, *cls;
    const float *bqkv, *bo, *ln1g, *ln1b, *b1, *b2, *ln2g, *ln2b;
    const float *outW, *outb, *olng, *olnb;
    // bf16 weights (converted into d_ws by pre-pass)
    const bf16 *Wqkv, *Wo, *W1, *W2;
    float* out;
};

__global__ void cvt_f32_bf16(const float* __restrict__ src, bf16* __restrict__ dst, int n) {
    int i = (blockIdx.x * blockDim.x + threadIdx.x) * 4;
    if (i < n) {
        floatx4 v = *(const floatx4*)&src[i];
        bf16x4 o;
        o[0] = (bf16)v[0]; o[1] = (bf16)v[1]; o[2] = (bf16)v[2]; o[3] = (bf16)v[3];
        *(bf16x4*)&dst[i] = o;
    }
}

__device__ inline float gelu_f(float x) {
    // tanh-form gelu: x * sigmoid(2*0.7978845608*(x + 0.044715 x^3)); max abs dev ~3e-4 vs exact
    float x3 = x * x * x;
    float y = 1.5957691216f * (x + 0.044715f * x3);
    float z = __expf(-y);
    return x / (1.f + z);
}

__device__ inline void ln_row(const bf16* src, bf16* dst, const float* g, const float* bb) {
    float v[64];
    float sum = 0.f, sq = 0.f;
#pragma unroll
    for (int kv = 0; kv < 8; ++kv) {
        bf16x8 x8 = *(const bf16x8*)&src[kv * 8];
#pragma unroll
        for (int e = 0; e < 8; ++e) {
            float f = (float)x8[e];
            v[kv * 8 + e] = f;
            sum += f;
            sq += f * f;
        }
    }
    float mean = sum * (1.f / 64.f);
    float var = sq * (1.f / 64.f) - mean * mean;
    float rs = rsqrtf(var + 1e-5f);
#pragma unroll
    for (int kv = 0; kv < 16; ++kv) {
        floatx4 g4 = *(const floatx4*)&g[kv * 4];
        floatx4 b4 = *(const floatx4*)&bb[kv * 4];
        bf16x4 o4;
#pragma unroll
        for (int e = 0; e < 4; ++e)
            o4[e] = (bf16)((v[kv * 4 + e] - mean) * rs * g4[e] + b4[e]);
        *(bf16x4*)&dst[kv * 4] = o4;
    }
}

__global__ __launch_bounds__(256, 2) void fused_tfm_kernel(Params p) {
    __shared__ __align__(16) bf16 xlds[RP * XS];      // 11520 B
    __shared__ __align__(16) bf16 qkvlds[RP * QS];    // 32000 B
    __shared__ __align__(16) bf16 attnlds[RP * XS];   // 11520 B
    __shared__ __align__(16) bf16 hlds[RP * HS];      // 21760 B
    __shared__ float sitlds[G * 128];                  // 1024 B

    const int tid = threadIdx.x;
    const int lane = tid & 63;
    const int w = tid >> 6;
    const int l15 = lane & 15;
    const int quad = lane >> 4;
    const int b0 = blockIdx.x * G;

    // ---------- phase 0a: token+pos embedding (shared by both items) into qkvlds scratch ----
    float* tokpos = (float*)qkvlds;  // 1536 floats = 6144 B < 32000 B
    for (int idx = tid; idx < 24 * 64; idx += 256) {
        int s = idx >> 6, d = idx & 63;
        float a = 0.f;
#pragma unroll
        for (int t = 0; t < 8; ++t) a += p.temb[p.tok[s * 8 + t] * 64 + d];
        tokpos[idx] = a * 0.125f + p.demb[idx] + p.traitb[d] + p.intentb[d];
    }
    __syncthreads();

    // ---------- phase 0b: build x in LDS (bf16) ----------
    for (int idx = tid; idx < G * S * 64; idx += 256) {
        int i = idx / (S * 64);
        int rem = idx - i * S * 64;
        int r = rem >> 6, d = rem & 63;
        int b = b0 + i;
        float v;
        if (r == 0) {
            v = p.cls[d];
        } else if (r <= 24) {
            int s = r - 1;
            v = tokpos[s * 64 + d] + p.traits[b * 48 + s * 2] * p.traitW[d * 2]
                + p.traits[b * 48 + s * 2 + 1] * p.traitW[d * 2 + 1]
                + p.relg[b * 24 + s] * p.intentW[d];
        } else {
            v = p.mem[b * 640 + (r - 25) * 64 + d];
        }
        xlds[(i * S + r) * XS + d] = (bf16)v;
    }
    // zero pad rows 70..79 of x and attn (x pads stay zero: LN only writes rows < 70)
    for (int idx = tid; idx < (RP - G * S) * 64; idx += 256) {
        int r = G * S + (idx >> 6), d = idx & 63;
        xlds[r * XS + d] = (bf16)0.f;
        attnlds[r * XS + d] = (bf16)0.f;
    }
    __syncthreads();

    // ---------- layers ----------
#pragma unroll 1
    for (int l = 0; l < NL; ++l) {
        const bf16* Wqkv_l = p.Wqkv + l * 192 * 64;
        const float* bqkv_l = p.bqkv + l * 192;
        const bf16* Wo_l = p.Wo + l * 64 * 64;
        const float* bo_l = p.bo + l * 64;
        const float* ln1g_l = p.ln1g + l * 64;
        const float* ln1b_l = p.ln1b + l * 64;
        const bf16* W1_l = p.W1 + l * 512 * 64;
        const float* b1_l = p.b1 + l * 512;
        const bf16* W2_l = p.W2 + l * 64 * 512;
        const float* b2_l = p.b2 + l * 64;
        const float* ln2g_l = p.ln2g + l * 64;
        const float* ln2b_l = p.ln2b + l * 64;

        // ===== QKV GEMM: (80x64) @ (64x192) =====
        {
            bf16x8 a[MT][2];
#pragma unroll
            for (int m = 0; m < MT; ++m)
#pragma unroll
                for (int kf = 0; kf < 2; ++kf)
                    a[m][kf] = *(const bf16x8*)&xlds[(m * 16 + l15) * XS + kf * 32 + quad * 8];
            for (int nt = w; nt < 12; nt += 4) {
                bf16x8 bb0 = *(const bf16x8*)&Wqkv_l[(nt * 16 + l15) * 64 + quad * 8];
                bf16x8 bb1 = *(const bf16x8*)&Wqkv_l[(nt * 16 + l15) * 64 + 32 + quad * 8];
                float bias = bqkv_l[nt * 16 + l15];
                floatx4 acc[MT];
#pragma unroll
                for (int m = 0; m < MT; ++m) {
                    acc[m] = {0.f, 0.f, 0.f, 0.f};
                    acc[m] = MFMA(a[m][0], bb0, acc[m]);
                    acc[m] = MFMA(a[m][1], bb1, acc[m]);
                }
#pragma unroll
                for (int m = 0; m < MT; ++m)
#pragma unroll
                    for (int r = 0; r < 4; ++r) {
                        int row = m * 16 + quad * 4 + r;
                        qkvlds[row * QS + nt * 16 + l15] = (bf16)(acc[m][r] + bias);
                    }
            }
        }
        __syncthreads();

        // ===== attention (VALU; hd=8, S=35) =====
        for (int t = tid; t < G * NH * S; t += 256) {
            int i = t / (NH * S);
            int rem = t - i * (NH * S);
            int h = rem / S;
            int q = rem - h * S;
            int rbase = i * S;
            bf16x8 qv8 = *(const bf16x8*)&qkvlds[(rbase + q) * QS + h * 8];
            float qf[8];
#pragma unroll
            for (int e = 0; e < 8; ++e) qf[e] = (float)qv8[e];
            float sc[S];
            float mx = -1e30f;
#pragma unroll
            for (int j = 0; j < S; ++j) {
                bf16x8 kv = *(const bf16x8*)&qkvlds[(rbase + j) * QS + 64 + h * 8];
                float s = 0.f;
#pragma unroll
                for (int e = 0; e < 8; ++e) s += qf[e] * (float)kv[e];
                s *= 0.35355339059f;
                sc[j] = s;
                mx = fmaxf(mx, s);
            }
            float lsum = 0.f;
#pragma unroll
            for (int j = 0; j < S; ++j) {
                sc[j] = __expf(sc[j] - mx);
                lsum += sc[j];
            }
            float inv = 1.f / lsum;
            float o[8] = {0.f, 0.f, 0.f, 0.f, 0.f, 0.f, 0.f, 0.f};
#pragma unroll
            for (int j = 0; j < S; ++j) {
                bf16x8 vv = *(const bf16x8*)&qkvlds[(rbase + j) * QS + 128 + h * 8];
#pragma unroll
                for (int e = 0; e < 8; ++e) o[e] += sc[j] * (float)vv[e];
            }
            bf16x8 ov;
#pragma unroll
            for (int e = 0; e < 8; ++e) ov[e] = (bf16)(o[e] * inv);
            *(bf16x8*)&attnlds[(rbase + q) * XS + h * 8] = ov;
        }
        __syncthreads();

        // ===== Wo GEMM + residual -> y (in hlds) =====
        {
            bf16x8 aa[MT][2];
#pragma unroll
            for (int m = 0; m < MT; ++m)
#pragma unroll
                for (int kf = 0; kf < 2; ++kf)
                    aa[m][kf] = *(const bf16x8*)&attnlds[(m * 16 + l15) * XS + kf * 32 + quad * 8];
            bf16x8 wb0 = *(const bf16x8*)&Wo_l[(w * 16 + l15) * 64 + quad * 8];
            bf16x8 wb1 = *(const bf16x8*)&Wo_l[(w * 16 + l15) * 64 + 32 + quad * 8];
            float bov = bo_l[w * 16 + l15];
            floatx4 oacc[MT];
#pragma unroll
            for (int m = 0; m < MT; ++m) {
                oacc[m] = {0.f, 0.f, 0.f, 0.f};
                oacc[m] = MFMA(aa[m][0], wb0, oacc[m]);
                oacc[m] = MFMA(aa[m][1], wb1, oacc[m]);
            }
            int col = w * 16 + l15;
#pragma unroll
            for (int m = 0; m < MT; ++m)
#pragma unroll
                for (int r = 0; r < 4; ++r) {
                    int row = m * 16 + quad * 4 + r;
                    hlds[row * XS + col] = (bf16)(oacc[m][r] + bov + (float)xlds[row * XS + col]);
                }
        }
        __syncthreads();

        // ===== LN1: y(hlds) -> x =====
        if (tid < G * S) ln_row(&hlds[tid * XS], &xlds[tid * XS], ln1g_l, ln1b_l);
        __syncthreads();

        // ===== FF: 4 chunks of 128, W2 accumulators persistent =====
        {
            bf16x8 a2[MT][2];
#pragma unroll
            for (int m = 0; m < MT; ++m)
#pragma unroll
                for (int kf = 0; kf < 2; ++kf)
                    a2[m][kf] = *(const bf16x8*)&xlds[(m * 16 + l15) * XS + kf * 32 + quad * 8];
            floatx4 facc[MT];
#pragma unroll
            for (int m = 0; m < MT; ++m) facc[m] = {0.f, 0.f, 0.f, 0.f};

#pragma unroll 1
            for (int c = 0; c < 4; ++c) {
                // h = gelu(x @ W1_chunk^T + b1)
                for (int ntl = w; ntl < 8; ntl += 4) {
                    int gc = c * 128 + ntl * 16 + l15;
                    bf16x8 w1b0 = *(const bf16x8*)&W1_l[gc * 64 + quad * 8];
                    bf16x8 w1b1 = *(const bf16x8*)&W1_l[gc * 64 + 32 + quad * 8];
                    float b1v = b1_l[gc];
                    floatx4 hacc[MT];
#pragma unroll
                    for (int m = 0; m < MT; ++m) {
                        hacc[m] = {0.f, 0.f, 0.f, 0.f};
                        hacc[m] = MFMA(a2[m][0], w1b0, hacc[m]);
                        hacc[m] = MFMA(a2[m][1], w1b1, hacc[m]);
                    }
#pragma unroll
                    for (int m = 0; m < MT; ++m)
#pragma unroll
                        for (int r = 0; r < 4; ++r) {
                            int row = m * 16 + quad * 4 + r;
                            hlds[row * HS + ntl * 16 + l15] = (bf16)gelu_f(hacc[m][r] + b1v);
                        }
                }
                __syncthreads();
                // facc += h_chunk @ W2_chunk^T
                bf16x8 w2b[4];
#pragma unroll
                for (int kf = 0; kf < 4; ++kf)
                    w2b[kf] = *(const bf16x8*)&W2_l[(w * 16 + l15) * 512 + c * 128 + kf * 32 + quad * 8];
#pragma unroll
                for (int m = 0; m < MT; ++m) {
                    bf16x8 ah0 = *(const bf16x8*)&hlds[(m * 16 + l15) * HS + 0 + quad * 8];
                    bf16x8 ah1 = *(const bf16x8*)&hlds[(m * 16 + l15) * HS + 32 + quad * 8];
                    bf16x8 ah2 = *(const bf16x8*)&hlds[(m * 16 + l15) * HS + 64 + quad * 8];
                    bf16x8 ah3 = *(const bf16x8*)&hlds[(m * 16 + l15) * HS + 96 + quad * 8];
                    facc[m] = MFMA(ah0, w2b[0], facc[m]);
                    facc[m] = MFMA(ah1, w2b[1], facc[m]);
                    facc[m] = MFMA(ah2, w2b[2], facc[m]);
                    facc[m] = MFMA(ah3, w2b[3], facc[m]);
                }
                __syncthreads();
            }

            // y2 = ff + b2 + x  -> attnlds
            float b2v = b2_l[w * 16 + l15];
            int col = w * 16 + l15;
#pragma unroll
            for (int m = 0; m < MT; ++m)
#pragma unroll
                for (int r = 0; r < 4; ++r) {
                    int row = m * 16 + quad * 4 + r;
                    attnlds[row * XS + col] = (bf16)(facc[m][r] + b2v + (float)xlds[row * XS + col]);
                }
        }
        __syncthreads();

        // ===== LN2: y2(attnlds) -> x =====
        if (tid < G * S) ln_row(&attnlds[tid * XS], &xlds[tid * XS], ln2g_l, ln2b_l);
        __syncthreads();
    }

    // ---------- head: situation = ln(x[:,0] @ outW^T + outb) ----------
    {
        int i = tid >> 7, j = tid & 127;
        const bf16* xr = &xlds[(i * S) * XS];
        float s = p.outb[j];
#pragma unroll
        for (int kv = 0; kv < 8; ++kv) {
            bf16x8 xv = *(const bf16x8*)&xr[kv * 8];
            floatx4 w0 = *(const floatx4*)&p.outW[j * 64 + kv * 8];
            floatx4 w1 = *(const floatx4*)&p.outW[j * 64 + kv * 8 + 4];
#pragma unroll
            for (int e = 0; e < 4; ++e) s += (float)xv[e] * w0[e];
#pragma unroll
            for (int e = 0; e < 4; ++e) s += (float)xv[4 + e] * w1[e];
        }
        sitlds[i * 128 + j] = s;
    }
    __syncthreads();

    // situation layernorm (wave 0 -> item 0, wave 1 -> item 1)
    if (w < 2) {
        int i = w;
        float v0 = sitlds[i * 128 + lane];
        float v1 = sitlds[i * 128 + 64 + lane];
        float sum = v0 + v1, sq = v0 * v0 + v1 * v1;
#pragma unroll
        for (int off = 32; off >= 1; off >>= 1) {
            sum += __shfl_xor(sum, off, 64);
            sq += __shfl_xor(sq, off, 64);
        }
        float mean = sum * (1.f / 128.f);
        float rs = rsqrtf(sq * (1.f / 128.f) - mean * mean + 1e-5f);
        int b = b0 + i;
        p.out[b * 128 + lane] = (v0 - mean) * rs * p.olng[lane] + p.olnb[lane];
        p.out[b * 128 + 64 + lane] = (v1 - mean) * rs * p.olng[64 + lane] + p.olnb[64 + lane];
    }

    // situation_sequence: x rows 1..24 -> fp32
    for (int pp = tid; pp < G * 384; pp += 256) {  // 384 = 24*64/4
        int i = pp / 384;
        int q = pp - i * 384;
        int s = q >> 4, dp = (q & 15) * 4;
        int b = b0 + i;
        bf16x4 xv = *(const bf16x4*)&xlds[(i * S + 1 + s) * XS + dp];
        floatx4 o = {(float)xv[0], (float)xv[1], (float)xv[2], (float)xv[3]};
        *(floatx4*)&p.out[SEQOFF + b * 1536 + s * 64 + dp] = o;
    }
    // new_memory rows 0..8: passthrough of memory_context rows 1..9 (fp32)
    for (int pp = tid; pp < G * 144; pp += 256) {  // 144 = 9*64/4
        int i = pp / 144;
        int q = pp - i * 144;
        int mr = q >> 4, dp = (q & 15) * 4;
        int b = b0 + i;
        floatx4 v = *(const floatx4*)&p.mem[b * 640 + (1 + mr) * 64 + dp];
        *(floatx4*)&p.out[MEMOFF + b * 640 + mr * 64 + dp] = v;
    }
    // new_memory row 9: mean of x rows 1..24
    if (tid < G * 64) {
        int i = tid >> 6, d = tid & 63;
        float s = 0.f;
#pragma unroll
        for (int sr = 0; sr < 24; ++sr) s += (float)xlds[(i * S + 1 + sr) * XS + d];
        p.out[MEMOFF + (b0 + i) * 640 + 576 + d] = s * (1.f / 24.f);
    }
}

extern "C" void kernel_launch(void* const* d_in, const int* in_sizes, int n_in,
                              void* d_out, int out_size, void* d_ws, size_t ws_size,
                              hipStream_t stream) {
    (void)in_sizes; (void)n_in; (void)out_size; (void)ws_size;

    // weight conversion pre-pass: fp32 -> bf16 into workspace
    bf16* ws = (bf16*)d_ws;
    bf16* wqkv_b = ws;                 // 36864
    bf16* wo_b = ws + 36864;           // 12288
    bf16* w1_b = ws + 49152;           // 98304
    bf16* w2_b = ws + 147456;          // 98304  (total 245760 bf16 = 480 KB)
    hipLaunchKernelGGL(cvt_f32_bf16, dim3(36), dim3(256), 0, stream, (const float*)d_in[11], wqkv_b, 36864);
    hipLaunchKernelGGL(cvt_f32_bf16, dim3(12), dim3(256), 0, stream, (const float*)d_in[13], wo_b, 12288);
    hipLaunchKernelGGL(cvt_f32_bf16, dim3(96), dim3(256), 0, stream, (const float*)d_in[17], w1_b, 98304);
    hipLaunchKernelGGL(cvt_f32_bf16, dim3(96), dim3(256), 0, stream, (const float*)d_in[19], w2_b, 98304);

    Params p;
    p.tok = (const int*)d_in[0];
    p.traits = (const float*)d_in[1];
    p.relg = (const float*)d_in[2];
    p.mem = (const float*)d_in[3];
    p.temb = (const float*)d_in[4];
    p.demb = (const float*)d_in[5];
    p.traitW = (const float*)d_in[6];
    p.traitb = (const float*)d_in[7];
    p.intentW = (const float*)d_in[8];
    p.intentb = (const float*)d_in[9];
    p.cls = (const float*)d_in[10];
    p.bqkv = (const float*)d_in[12];
    p.bo = (const float*)d_in[14];
    p.ln1g = (const float*)d_in[15];
    p.ln1b = (const float*)d_in[16];
    p.b1 = (const float*)d_in[18];
    p.b2 = (const float*)d_in[20];
    p.ln2g = (const float*)d_in[21];
    p.ln2b = (const float*)d_in[22];
    p.outW = (const float*)d_in[23];
    p.outb = (const float*)d_in[24];
    p.olng = (const float*)d_in[25];
    p.olnb = (const float*)d_in[26];
    p.Wqkv = wqkv_b;
    p.Wo = wo_b;
    p.W1 = w1_b;
    p.W2 = w2_b;
    p.out = (float*)d_out;

    hipLaunchKernelGGL(fused_tfm_kernel, dim3(4096 / G), dim3(256), 0, stream, p);
}

// Round 3
// 626.357 us; speedup vs baseline: 1.0227x; 1.0227x over previous
//
#include <hip/hip_runtime.h>

typedef __bf16 bf16;
typedef __bf16 bf16x4 __attribute__((ext_vector_type(4)));
typedef __bf16 bf16x8 __attribute__((ext_vector_type(8)));
typedef float floatx4 __attribute__((ext_vector_type(4)));

#define MFMA(a, b, c) __builtin_amdgcn_mfma_f32_16x16x32_bf16((a), (b), (c), 0, 0, 0)

// Problem constants
constexpr int S = 35;        // 1 cls + 24 dims + 10 mem
constexpr int NH = 8;
constexpr int NL = 3;
constexpr int G = 2;         // batch items per block
constexpr int RP = 80;       // padded rows (G*35 = 70 -> 5 m-tiles)
constexpr int MT = 5;        // MFMA m-tiles
constexpr int XS = 72;       // row stride for 64-col buffers (144B rows -> 2-way banks, free)
constexpr int HS = 136;      // ff-chunk LDS stride (chunk 128)
constexpr int BUF = RP * XS; // 5760 elems per 80x64 buffer
constexpr int SEQOFF = 4096 * 128;                 // 524288
constexpr int MEMOFF = SEQOFF + 4096 * 24 * 64;    // 6815744

struct Params {
    const int* tok;
    // fp32 inputs
    const float *traits, *relg, *mem, *temb, *demb, *traitW, *traitb, *intentW, *intentb, *cls;
    const float *bqkv, *bo, *ln1g, *ln1b, *b1, *b2, *ln2g, *ln2b;
    const float *outW, *outb, *olng, *olnb;
    // bf16 weights (converted into d_ws by pre-pass)
    const bf16 *Wqkv, *Wo, *W1, *W2;
    float* out;
};

// single merged fp32->bf16 conversion for all 4 weight tensors
// ranges (elems): wqkv [0,36864) wo [36864,49152) w1 [49152,147456) w2 [147456,245760)
__global__ void cvt_all(const float* __restrict__ wqkv, const float* __restrict__ wo,
                        const float* __restrict__ w1, const float* __restrict__ w2,
                        bf16* __restrict__ dst) {
    int i = (blockIdx.x * 256 + threadIdx.x) * 4;
    const float* src;
    int off;
    if (i < 36864)       { src = wqkv; off = 0; }
    else if (i < 49152)  { src = wo;   off = 36864; }
    else if (i < 147456) { src = w1;   off = 49152; }
    else                 { src = w2;   off = 147456; }
    floatx4 v = *(const floatx4*)&src[i - off];
    bf16x4 o;
    o[0] = (bf16)v[0]; o[1] = (bf16)v[1]; o[2] = (bf16)v[2]; o[3] = (bf16)v[3];
    *(bf16x4*)&dst[i] = o;
}

__device__ inline float gelu_f(float x) {
    // tanh-form gelu: max abs dev ~3e-4 vs exact erf form
    float x3 = x * x * x;
    float y = 1.5957691216f * (x + 0.044715f * x3);
    float z = __expf(-y);
    return x / (1.f + z);
}

__device__ inline void ln_row(const bf16* src, bf16* dst, const float* g, const float* bb) {
    float v[64];
    float sum = 0.f, sq = 0.f;
#pragma unroll
    for (int kv = 0; kv < 8; ++kv) {
        bf16x8 x8 = *(const bf16x8*)&src[kv * 8];
#pragma unroll
        for (int e = 0; e < 8; ++e) {
            float f = (float)x8[e];
            v[kv * 8 + e] = f;
            sum += f;
            sq += f * f;
        }
    }
    float mean = sum * (1.f / 64.f);
    float var = sq * (1.f / 64.f) - mean * mean;
    float rs = rsqrtf(var + 1e-5f);
#pragma unroll
    for (int kv = 0; kv < 16; ++kv) {
        floatx4 g4 = *(const floatx4*)&g[kv * 4];
        floatx4 b4 = *(const floatx4*)&bb[kv * 4];
        bf16x4 o4;
#pragma unroll
        for (int e = 0; e < 4; ++e)
            o4[e] = (bf16)((v[kv * 4 + e] - mean) * rs * g4[e] + b4[e]);
        *(bf16x4*)&dst[kv * 4] = o4;
    }
}

__global__ __launch_bounds__(256, 3) void fused_tfm_kernel(Params p) {
    // LDS budget: 11520 + 34560 + 1024 = 47104 B -> 3 blocks/CU
    __shared__ __align__(16) bf16 xlds[BUF];          // 11520 B : x (residual stream)
    __shared__ __align__(16) bf16 scratch[3 * BUF];   // 34560 B : q|k|v, then h / y / y2
    __shared__ float sitlds[G * 128];                 // 1024 B

    bf16* qbuf = scratch;                 // [0, 5760)
    bf16* kbuf = scratch + BUF;           // [5760, 11520)
    bf16* vbuf = scratch + 2 * BUF;       // [11520, 17280)  (also y / y2 home)
    bf16* hbuf = scratch;                 // FF h-chunk: 80*136 = 10880 elems, overlays dead q|k

    const int tid = threadIdx.x;
    const int lane = tid & 63;
    const int w = tid >> 6;
    const int l15 = lane & 15;
    const int quad = lane >> 4;
    const int b0 = blockIdx.x * G;

    // ---------- phase 0a: token+pos embedding (shared by both items) into scratch ----
    float* tokpos = (float*)scratch;  // 1536 floats = 6144 B
    for (int idx = tid; idx < 24 * 64; idx += 256) {
        int s = idx >> 6, d = idx & 63;
        float a = 0.f;
#pragma unroll
        for (int t = 0; t < 8; ++t) a += p.temb[p.tok[s * 8 + t] * 64 + d];
        tokpos[idx] = a * 0.125f + p.demb[idx] + p.traitb[d] + p.intentb[d];
    }
    __syncthreads();

    // ---------- phase 0b: build x in LDS (bf16) ----------
    for (int idx = tid; idx < G * S * 64; idx += 256) {
        int i = idx / (S * 64);
        int rem = idx - i * S * 64;
        int r = rem >> 6, d = rem & 63;
        int b = b0 + i;
        float v;
        if (r == 0) {
            v = p.cls[d];
        } else if (r <= 24) {
            int s = r - 1;
            v = tokpos[s * 64 + d] + p.traits[b * 48 + s * 2] * p.traitW[d * 2]
                + p.traits[b * 48 + s * 2 + 1] * p.traitW[d * 2 + 1]
                + p.relg[b * 24 + s] * p.intentW[d];
        } else {
            v = p.mem[b * 640 + (r - 25) * 64 + d];
        }
        xlds[(i * S + r) * XS + d] = (bf16)v;
    }
    // zero pad rows 70..79 of x (stay zero across all layers: LN only writes rows < 70)
    for (int idx = tid; idx < (RP - G * S) * 64; idx += 256) {
        int r = G * S + (idx >> 6), d = idx & 63;
        xlds[r * XS + d] = (bf16)0.f;
    }
    __syncthreads();

    // ---------- layers ----------
#pragma unroll 1
    for (int l = 0; l < NL; ++l) {
        const bf16* Wqkv_l = p.Wqkv + l * 192 * 64;
        const float* bqkv_l = p.bqkv + l * 192;
        const bf16* Wo_l = p.Wo + l * 64 * 64;
        const float* bo_l = p.bo + l * 64;
        const float* ln1g_l = p.ln1g + l * 64;
        const float* ln1b_l = p.ln1b + l * 64;
        const bf16* W1_l = p.W1 + l * 512 * 64;
        const float* b1_l = p.b1 + l * 512;
        const bf16* W2_l = p.W2 + l * 64 * 512;
        const float* b2_l = p.b2 + l * 64;
        const float* ln2g_l = p.ln2g + l * 64;
        const float* ln2b_l = p.ln2b + l * 64;

        // ===== QKV GEMM: (80x64) @ (64x192) -> q|k|v buffers =====
        {
            bf16x8 a[MT][2];
#pragma unroll
            for (int m = 0; m < MT; ++m)
#pragma unroll
                for (int kf = 0; kf < 2; ++kf)
                    a[m][kf] = *(const bf16x8*)&xlds[(m * 16 + l15) * XS + kf * 32 + quad * 8];
            for (int nt = w; nt < 12; nt += 4) {
                bf16x8 bb0 = *(const bf16x8*)&Wqkv_l[(nt * 16 + l15) * 64 + quad * 8];
                bf16x8 bb1 = *(const bf16x8*)&Wqkv_l[(nt * 16 + l15) * 64 + 32 + quad * 8];
                float bias = bqkv_l[nt * 16 + l15];
                floatx4 acc[MT];
#pragma unroll
                for (int m = 0; m < MT; ++m) {
                    acc[m] = {0.f, 0.f, 0.f, 0.f};
                    acc[m] = MFMA(a[m][0], bb0, acc[m]);
                    acc[m] = MFMA(a[m][1], bb1, acc[m]);
                }
                bf16* dst = scratch + (nt >> 2) * BUF;
                int col = (nt & 3) * 16 + l15;
#pragma unroll
                for (int m = 0; m < MT; ++m)
#pragma unroll
                    for (int r = 0; r < 4; ++r) {
                        int row = m * 16 + quad * 4 + r;
                        dst[row * XS + col] = (bf16)(acc[m][r] + bias);
                    }
            }
        }
        __syncthreads();

        // ===== attention (VALU; hd=8, S=35); output IN PLACE into q slot =====
        for (int t = tid; t < G * NH * S; t += 256) {
            int i = t / (NH * S);
            int rem = t - i * (NH * S);
            int h = rem / S;
            int q = rem - h * S;
            int rbase = i * S;
            bf16x8 qv8 = *(const bf16x8*)&qbuf[(rbase + q) * XS + h * 8];
            float qf[8];
#pragma unroll
            for (int e = 0; e < 8; ++e) qf[e] = (float)qv8[e];
            float sc[S];
            float mx = -1e30f;
#pragma unroll
            for (int j = 0; j < S; ++j) {
                bf16x8 kv = *(const bf16x8*)&kbuf[(rbase + j) * XS + h * 8];
                float s = 0.f;
#pragma unroll
                for (int e = 0; e < 8; ++e) s += qf[e] * (float)kv[e];
                s *= 0.35355339059f;
                sc[j] = s;
                mx = fmaxf(mx, s);
            }
            float lsum = 0.f;
#pragma unroll
            for (int j = 0; j < S; ++j) {
                sc[j] = __expf(sc[j] - mx);
                lsum += sc[j];
            }
            float inv = 1.f / lsum;
            float o[8] = {0.f, 0.f, 0.f, 0.f, 0.f, 0.f, 0.f, 0.f};
#pragma unroll
            for (int j = 0; j < S; ++j) {
                bf16x8 vv = *(const bf16x8*)&vbuf[(rbase + j) * XS + h * 8];
#pragma unroll
                for (int e = 0; e < 8; ++e) o[e] += sc[j] * (float)vv[e];
            }
            bf16x8 ov;
#pragma unroll
            for (int e = 0; e < 8; ++e) ov[e] = (bf16)(o[e] * inv);
            *(bf16x8*)&qbuf[(rbase + q) * XS + h * 8] = ov;  // in-place: slot owned by this thread
        }
        __syncthreads();

        // ===== Wo GEMM + residual -> y (in vbuf; k,v dead) =====
        {
            bf16x8 aa[MT][2];
#pragma unroll
            for (int m = 0; m < MT; ++m)
#pragma unroll
                for (int kf = 0; kf < 2; ++kf)
                    aa[m][kf] = *(const bf16x8*)&qbuf[(m * 16 + l15) * XS + kf * 32 + quad * 8];
            bf16x8 wb0 = *(const bf16x8*)&Wo_l[(w * 16 + l15) * 64 + quad * 8];
            bf16x8 wb1 = *(const bf16x8*)&Wo_l[(w * 16 + l15) * 64 + 32 + quad * 8];
            float bov = bo_l[w * 16 + l15];
            floatx4 oacc[MT];
#pragma unroll
            for (int m = 0; m < MT; ++m) {
                oacc[m] = {0.f, 0.f, 0.f, 0.f};
                oacc[m] = MFMA(aa[m][0], wb0, oacc[m]);
                oacc[m] = MFMA(aa[m][1], wb1, oacc[m]);
            }
            int col = w * 16 + l15;
#pragma unroll
            for (int m = 0; m < MT; ++m)
#pragma unroll
                for (int r = 0; r < 4; ++r) {
                    int row = m * 16 + quad * 4 + r;
                    vbuf[row * XS + col] = (bf16)(oacc[m][r] + bov + (float)xlds[row * XS + col]);
                }
        }
        __syncthreads();

        // ===== LN1: y(vbuf) -> x =====
        if (tid < G * S) ln_row(&vbuf[tid * XS], &xlds[tid * XS], ln1g_l, ln1b_l);
        __syncthreads();

        // ===== FF: 4 chunks of 128, W2 accumulators persistent; h overlays q|k =====
        {
            bf16x8 a2[MT][2];
#pragma unroll
            for (int m = 0; m < MT; ++m)
#pragma unroll
                for (int kf = 0; kf < 2; ++kf)
                    a2[m][kf] = *(const bf16x8*)&xlds[(m * 16 + l15) * XS + kf * 32 + quad * 8];
            floatx4 facc[MT];
#pragma unroll
            for (int m = 0; m < MT; ++m) facc[m] = {0.f, 0.f, 0.f, 0.f};

#pragma unroll 1
            for (int c = 0; c < 4; ++c) {
                // h = gelu(x @ W1_chunk^T + b1)
                for (int ntl = w; ntl < 8; ntl += 4) {
                    int gc = c * 128 + ntl * 16 + l15;
                    bf16x8 w1b0 = *(const bf16x8*)&W1_l[gc * 64 + quad * 8];
                    bf16x8 w1b1 = *(const bf16x8*)&W1_l[gc * 64 + 32 + quad * 8];
                    float b1v = b1_l[gc];
                    floatx4 hacc[MT];
#pragma unroll
                    for (int m = 0; m < MT; ++m) {
                        hacc[m] = {0.f, 0.f, 0.f, 0.f};
                        hacc[m] = MFMA(a2[m][0], w1b0, hacc[m]);
                        hacc[m] = MFMA(a2[m][1], w1b1, hacc[m]);
                    }
#pragma unroll
                    for (int m = 0; m < MT; ++m)
#pragma unroll
                        for (int r = 0; r < 4; ++r) {
                            int row = m * 16 + quad * 4 + r;
                            hbuf[row * HS + ntl * 16 + l15] = (bf16)gelu_f(hacc[m][r] + b1v);
                        }
                }
                __syncthreads();
                // facc += h_chunk @ W2_chunk^T
                bf16x8 w2b[4];
#pragma unroll
                for (int kf = 0; kf < 4; ++kf)
                    w2b[kf] = *(const bf16x8*)&W2_l[(w * 16 + l15) * 512 + c * 128 + kf * 32 + quad * 8];
#pragma unroll
                for (int m = 0; m < MT; ++m) {
                    bf16x8 ah0 = *(const bf16x8*)&hbuf[(m * 16 + l15) * HS + 0 + quad * 8];
                    bf16x8 ah1 = *(const bf16x8*)&hbuf[(m * 16 + l15) * HS + 32 + quad * 8];
                    bf16x8 ah2 = *(const bf16x8*)&hbuf[(m * 16 + l15) * HS + 64 + quad * 8];
                    bf16x8 ah3 = *(const bf16x8*)&hbuf[(m * 16 + l15) * HS + 96 + quad * 8];
                    facc[m] = MFMA(ah0, w2b[0], facc[m]);
                    facc[m] = MFMA(ah1, w2b[1], facc[m]);
                    facc[m] = MFMA(ah2, w2b[2], facc[m]);
                    facc[m] = MFMA(ah3, w2b[3], facc[m]);
                }
                __syncthreads();
            }

            // y2 = ff + b2 + x  -> vbuf (y dead after LN1)
            float b2v = b2_l[w * 16 + l15];
            int col = w * 16 + l15;
#pragma unroll
            for (int m = 0; m < MT; ++m)
#pragma unroll
                for (int r = 0; r < 4; ++r) {
                    int row = m * 16 + quad * 4 + r;
                    vbuf[row * XS + col] = (bf16)(facc[m][r] + b2v + (float)xlds[row * XS + col]);
                }
        }
        __syncthreads();

        // ===== LN2: y2(vbuf) -> x =====
        if (tid < G * S) ln_row(&vbuf[tid * XS], &xlds[tid * XS], ln2g_l, ln2b_l);
        __syncthreads();
    }

    // ---------- head: situation = ln(x[:,0] @ outW^T + outb) ----------
    {
        int i = tid >> 7, j = tid & 127;
        const bf16* xr = &xlds[(i * S) * XS];
        float s = p.outb[j];
#pragma unroll
        for (int kv = 0; kv < 8; ++kv) {
            bf16x8 xv = *(const bf16x8*)&xr[kv * 8];
            floatx4 w0 = *(const floatx4*)&p.outW[j * 64 + kv * 8];
            floatx4 w1 = *(const floatx4*)&p.outW[j * 64 + kv * 8 + 4];
#pragma unroll
            for (int e = 0; e < 4; ++e) s += (float)xv[e] * w0[e];
#pragma unroll
            for (int e = 0; e < 4; ++e) s += (float)xv[4 + e] * w1[e];
        }
        sitlds[i * 128 + j] = s;
    }
    __syncthreads();

    // situation layernorm (wave 0 -> item 0, wave 1 -> item 1)
    if (w < 2) {
        int i = w;
        float v0 = sitlds[i * 128 + lane];
        float v1 = sitlds[i * 128 + 64 + lane];
        float sum = v0 + v1, sq = v0 * v0 + v1 * v1;
#pragma unroll
        for (int off = 32; off >= 1; off >>= 1) {
            sum += __shfl_xor(sum, off, 64);
            sq += __shfl_xor(sq, off, 64);
        }
        float mean = sum * (1.f / 128.f);
        float rs = rsqrtf(sq * (1.f / 128.f) - mean * mean + 1e-5f);
        int b = b0 + i;
        p.out[b * 128 + lane] = (v0 - mean) * rs * p.olng[lane] + p.olnb[lane];
        p.out[b * 128 + 64 + lane] = (v1 - mean) * rs * p.olng[64 + lane] + p.olnb[64 + lane];
    }

    // situation_sequence: x rows 1..24 -> fp32
    for (int pp = tid; pp < G * 384; pp += 256) {  // 384 = 24*64/4
        int i = pp / 384;
        int q = pp - i * 384;
        int s = q >> 4, dp = (q & 15) * 4;
        int b = b0 + i;
        bf16x4 xv = *(const bf16x4*)&xlds[(i * S + 1 + s) * XS + dp];
        floatx4 o = {(float)xv[0], (float)xv[1], (float)xv[2], (float)xv[3]};
        *(floatx4*)&p.out[SEQOFF + b * 1536 + s * 64 + dp] = o;
    }
    // new_memory rows 0..8: passthrough of memory_context rows 1..9 (fp32)
    for (int pp = tid; pp < G * 144; pp += 256) {  // 144 = 9*64/4
        int i = pp / 144;
        int q = pp - i * 144;
        int mr = q >> 4, dp = (q & 15) * 4;
        int b = b0 + i;
        floatx4 v = *(const floatx4*)&p.mem[b * 640 + (1 + mr) * 64 + dp];
        *(floatx4*)&p.out[MEMOFF + b * 640 + mr * 64 + dp] = v;
    }
    // new_memory row 9: mean of x rows 1..24
    if (tid < G * 64) {
        int i = tid >> 6, d = tid & 63;
        float s = 0.f;
#pragma unroll
        for (int sr = 0; sr < 24; ++sr) s += (float)xlds[(i * S + 1 + sr) * XS + d];
        p.out[MEMOFF + (b0 + i) * 640 + 576 + d] = s * (1.f / 24.f);
    }
}

extern "C" void kernel_launch(void* const* d_in, const int* in_sizes, int n_in,
                              void* d_out, int out_size, void* d_ws, size_t ws_size,
                              hipStream_t stream) {
    (void)in_sizes; (void)n_in; (void)out_size; (void)ws_size;

    // weight conversion pre-pass: fp32 -> bf16 into workspace (one kernel)
    bf16* ws = (bf16*)d_ws;
    hipLaunchKernelGGL(cvt_all, dim3(240), dim3(256), 0, stream,
                       (const float*)d_in[11], (const float*)d_in[13],
                       (const float*)d_in[17], (const float*)d_in[19], ws);

    Params p;
    p.tok = (const int*)d_in[0];
    p.traits = (const float*)d_in[1];
    p.relg = (const float*)d_in[2];
    p.mem = (const float*)d_in[3];
    p.temb = (const float*)d_in[4];
    p.demb = (const float*)d_in[5];
    p.traitW = (const float*)d_in[6];
    p.traitb = (const float*)d_in[7];
    p.intentW = (const float*)d_in[8];
    p.intentb = (const float*)d_in[9];
    p.cls = (const float*)d_in[10];
    p.bqkv = (const float*)d_in[12];
    p.bo = (const float*)d_in[14];
    p.ln1g = (const float*)d_in[15];
    p.ln1b = (const float*)d_in[16];
    p.b1 = (const float*)d_in[18];
    p.b2 = (const float*)d_in[20];
    p.ln2g = (const float*)d_in[21];
    p.ln2b = (const float*)d_in[22];
    p.outW = (const float*)d_in[23];
    p.outb = (const float*)d_in[24];
    p.olng = (const float*)d_in[25];
    p.olnb = (const float*)d_in[26];
    p.Wqkv = ws;                 // 36864
    p.Wo = ws + 36864;           // 12288
    p.W1 = ws + 49152;           // 98304
    p.W2 = ws + 147456;          // 98304
    p.out = (float*)d_out;

    hipLaunchKernelGGL(fused_tfm_kernel, dim3(4096 / G), dim3(256), 0, stream, p);
}

// Round 4
// 523.276 us; speedup vs baseline: 1.2242x; 1.1970x over previous
//
#include <hip/hip_runtime.h>

typedef _Float16 f16;
typedef _Float16 f16x2 __attribute__((ext_vector_type(2)));
typedef _Float16 f16x4 __attribute__((ext_vector_type(4)));
typedef _Float16 f16x8 __attribute__((ext_vector_type(8)));
typedef float floatx4 __attribute__((ext_vector_type(4)));

#define MFMA(a, b, c) __builtin_amdgcn_mfma_f32_16x16x32_f16((a), (b), (c), 0, 0, 0)

// Problem constants
constexpr int S = 35;        // 1 cls + 24 dims + 10 mem
constexpr int NH = 8;
constexpr int NL = 3;
constexpr int G = 2;         // batch items per block
constexpr int RP = 80;       // padded rows (G*35 = 70 -> 5 m-tiles)
constexpr int MT = 5;        // MFMA m-tiles
constexpr int XS = 72;       // row stride for 64-col buffers (144B rows -> 2-way banks, free)
constexpr int HS = 136;      // ff-chunk LDS stride (chunk 128)
constexpr int BUF = RP * XS; // 5760 elems per 80x64 buffer
constexpr int SEQOFF = 4096 * 128;                 // 524288
constexpr int MEMOFF = SEQOFF + 4096 * 24 * 64;    // 6815744

struct Params {
    const int* tok;
    // fp32 inputs
    const float *traits, *relg, *mem, *temb, *demb, *traitW, *traitb, *intentW, *intentb, *cls;
    const float *bqkv, *bo, *ln1g, *ln1b, *b1, *b2, *ln2g, *ln2b;
    const float *outW, *outb, *olng, *olnb;
    // f16 weights (converted into d_ws by pre-pass)
    const f16 *Wqkv, *Wo, *W1, *W2;
    float* out;
};

// single merged fp32->f16 conversion for all 4 weight tensors
// ranges (elems): wqkv [0,36864) wo [36864,49152) w1 [49152,147456) w2 [147456,245760)
__global__ void cvt_all(const float* __restrict__ wqkv, const float* __restrict__ wo,
                        const float* __restrict__ w1, const float* __restrict__ w2,
                        f16* __restrict__ dst) {
    int i = (blockIdx.x * 256 + threadIdx.x) * 4;
    const float* src;
    int off;
    if (i < 36864)       { src = wqkv; off = 0; }
    else if (i < 49152)  { src = wo;   off = 36864; }
    else if (i < 147456) { src = w1;   off = 49152; }
    else                 { src = w2;   off = 147456; }
    floatx4 v = *(const floatx4*)&src[i - off];
    f16x4 o;
    o[0] = (f16)v[0]; o[1] = (f16)v[1]; o[2] = (f16)v[2]; o[3] = (f16)v[3];
    *(f16x4*)&dst[i] = o;
}

__device__ inline float gelu_f(float x) {
    // tanh-form gelu via sigmoid; rcp instead of exact divide
    float x3 = x * x * x;
    float y = 1.5957691216f * (x + 0.044715f * x3);
    float z = __expf(-y);
    return x * __builtin_amdgcn_rcpf(1.f + z);
}

__device__ inline void ln_row(const f16* src, f16* dst, const float* g, const float* bb) {
    float v[64];
    float sum = 0.f, sq = 0.f;
#pragma unroll
    for (int kv = 0; kv < 8; ++kv) {
        f16x8 x8 = *(const f16x8*)&src[kv * 8];
#pragma unroll
        for (int e = 0; e < 8; ++e) {
            float f = (float)x8[e];
            v[kv * 8 + e] = f;
            sum += f;
            sq += f * f;
        }
    }
    float mean = sum * (1.f / 64.f);
    float var = sq * (1.f / 64.f) - mean * mean;
    float rs = rsqrtf(var + 1e-5f);
#pragma unroll
    for (int kv = 0; kv < 16; ++kv) {
        floatx4 g4 = *(const floatx4*)&g[kv * 4];
        floatx4 b4 = *(const floatx4*)&bb[kv * 4];
        f16x4 o4;
#pragma unroll
        for (int e = 0; e < 4; ++e)
            o4[e] = (f16)((v[kv * 4 + e] - mean) * rs * g4[e] + b4[e]);
        *(f16x4*)&dst[kv * 4] = o4;
    }
}

__global__ __launch_bounds__(256, 3) void fused_tfm_kernel(Params p) {
    // LDS budget: 11520 + 34560 + 1024 = 47104 B -> 3 blocks/CU
    __shared__ __align__(16) f16 xlds[BUF];          // 11520 B : x (residual stream)
    __shared__ __align__(16) f16 scratch[3 * BUF];   // 34560 B : q|k|v, then h / y / y2
    __shared__ float sitlds[G * 128];                // 1024 B

    f16* qbuf = scratch;                 // [0, 5760)
    f16* kbuf = scratch + BUF;           // [5760, 11520)
    f16* vbuf = scratch + 2 * BUF;       // [11520, 17280)  (also y / y2 home)
    f16* hbuf = scratch;                 // FF h-chunk: 80*136 elems, overlays dead q|k

    const int tid = threadIdx.x;
    const int lane = tid & 63;
    const int w = tid >> 6;
    const int l15 = lane & 15;
    const int quad = lane >> 4;
    const int b0 = blockIdx.x * G;

    // ---------- phase 0a: token+pos embedding (shared by both items) into scratch ----
    float* tokpos = (float*)scratch;  // 1536 floats = 6144 B
    for (int idx = tid; idx < 24 * 64; idx += 256) {
        int s = idx >> 6, d = idx & 63;
        float a = 0.f;
#pragma unroll
        for (int t = 0; t < 8; ++t) a += p.temb[p.tok[s * 8 + t] * 64 + d];
        tokpos[idx] = a * 0.125f + p.demb[idx] + p.traitb[d] + p.intentb[d];
    }
    __syncthreads();

    // ---------- phase 0b: build x in LDS (f16) ----------
    for (int idx = tid; idx < G * S * 64; idx += 256) {
        int i = idx / (S * 64);
        int rem = idx - i * S * 64;
        int r = rem >> 6, d = rem & 63;
        int b = b0 + i;
        float v;
        if (r == 0) {
            v = p.cls[d];
        } else if (r <= 24) {
            int s = r - 1;
            v = tokpos[s * 64 + d] + p.traits[b * 48 + s * 2] * p.traitW[d * 2]
                + p.traits[b * 48 + s * 2 + 1] * p.traitW[d * 2 + 1]
                + p.relg[b * 24 + s] * p.intentW[d];
        } else {
            v = p.mem[b * 640 + (r - 25) * 64 + d];
        }
        xlds[(i * S + r) * XS + d] = (f16)v;
    }
    // zero pad rows 70..79 of x (stay zero across all layers: LN only writes rows < 70)
    for (int idx = tid; idx < (RP - G * S) * 64; idx += 256) {
        int r = G * S + (idx >> 6), d = idx & 63;
        xlds[r * XS + d] = (f16)0.f;
    }
    __syncthreads();

    // ---------- layers ----------
#pragma unroll 1
    for (int l = 0; l < NL; ++l) {
        const f16* Wqkv_l = p.Wqkv + l * 192 * 64;
        const float* bqkv_l = p.bqkv + l * 192;
        const f16* Wo_l = p.Wo + l * 64 * 64;
        const float* bo_l = p.bo + l * 64;
        const float* ln1g_l = p.ln1g + l * 64;
        const float* ln1b_l = p.ln1b + l * 64;
        const f16* W1_l = p.W1 + l * 512 * 64;
        const float* b1_l = p.b1 + l * 512;
        const f16* W2_l = p.W2 + l * 64 * 512;
        const float* b2_l = p.b2 + l * 64;
        const float* ln2g_l = p.ln2g + l * 64;
        const float* ln2b_l = p.ln2b + l * 64;

        // ===== QKV GEMM: (80x64) @ (64x192) -> q|k|v buffers =====
        {
            f16x8 a[MT][2];
#pragma unroll
            for (int m = 0; m < MT; ++m)
#pragma unroll
                for (int kf = 0; kf < 2; ++kf)
                    a[m][kf] = *(const f16x8*)&xlds[(m * 16 + l15) * XS + kf * 32 + quad * 8];
#pragma unroll
            for (int nt = w; nt < 12; nt += 4) {
                f16x8 bb0 = *(const f16x8*)&Wqkv_l[(nt * 16 + l15) * 64 + quad * 8];
                f16x8 bb1 = *(const f16x8*)&Wqkv_l[(nt * 16 + l15) * 64 + 32 + quad * 8];
                float bias = bqkv_l[nt * 16 + l15];
                floatx4 acc[MT];
#pragma unroll
                for (int m = 0; m < MT; ++m) {
                    acc[m] = {0.f, 0.f, 0.f, 0.f};
                    acc[m] = MFMA(a[m][0], bb0, acc[m]);
                    acc[m] = MFMA(a[m][1], bb1, acc[m]);
                }
                f16* dst = scratch + (nt >> 2) * BUF;
                int col = (nt & 3) * 16 + l15;
#pragma unroll
                for (int m = 0; m < MT; ++m)
#pragma unroll
                    for (int r = 0; r < 4; ++r) {
                        int row = m * 16 + quad * 4 + r;
                        dst[row * XS + col] = (f16)(acc[m][r] + bias);
                    }
            }
        }
        __syncthreads();

        // ===== attention (packed f16 VALU; hd=8, S=35); output IN PLACE into q slot =====
        for (int t = tid; t < G * NH * S; t += 256) {
            int i = t / (NH * S);
            int rem = t - i * (NH * S);
            int h = rem / S;
            int q = rem - h * S;
            int rbase = i * S;
            const f16x2* qp = (const f16x2*)&qbuf[(rbase + q) * XS + h * 8];
            f16x2 q0 = qp[0], q1 = qp[1], q2 = qp[2], q3 = qp[3];
            float sc[S];
            float mx = -1e30f;
#pragma unroll
            for (int j = 0; j < S; ++j) {
                const f16x2* kp = (const f16x2*)&kbuf[(rbase + j) * XS + h * 8];
                f16x2 acc2 = q0 * kp[0];
                acc2 = q1 * kp[1] + acc2;
                acc2 = q2 * kp[2] + acc2;
                acc2 = q3 * kp[3] + acc2;
                float s = ((float)acc2[0] + (float)acc2[1]) * 0.35355339059f;
                sc[j] = s;
                mx = fmaxf(mx, s);
            }
            float lsum = 0.f;
#pragma unroll
            for (int j = 0; j < S; ++j) {
                sc[j] = __expf(sc[j] - mx);
                lsum += sc[j];
            }
            f16x2 o0 = {0.f, 0.f}, o1 = {0.f, 0.f}, o2 = {0.f, 0.f}, o3 = {0.f, 0.f};
#pragma unroll
            for (int j = 0; j < S; ++j) {
                const f16x2* vp = (const f16x2*)&vbuf[(rbase + j) * XS + h * 8];
                f16 sj = (f16)sc[j];
                f16x2 s2 = {sj, sj};
                o0 = vp[0] * s2 + o0;
                o1 = vp[1] * s2 + o1;
                o2 = vp[2] * s2 + o2;
                o3 = vp[3] * s2 + o3;
            }
            f16 invh = (f16)__builtin_amdgcn_rcpf(lsum);
            f16x2 inv2 = {invh, invh};
            o0 *= inv2; o1 *= inv2; o2 *= inv2; o3 *= inv2;
            f16x8 ov;
            ov[0] = o0[0]; ov[1] = o0[1]; ov[2] = o1[0]; ov[3] = o1[1];
            ov[4] = o2[0]; ov[5] = o2[1]; ov[6] = o3[0]; ov[7] = o3[1];
            *(f16x8*)&qbuf[(rbase + q) * XS + h * 8] = ov;  // in-place: slot owned by this thread
        }
        __syncthreads();

        // ===== Wo GEMM + residual -> y (in vbuf; k,v dead) =====
        {
            f16x8 aa[MT][2];
#pragma unroll
            for (int m = 0; m < MT; ++m)
#pragma unroll
                for (int kf = 0; kf < 2; ++kf)
                    aa[m][kf] = *(const f16x8*)&qbuf[(m * 16 + l15) * XS + kf * 32 + quad * 8];
            f16x8 wb0 = *(const f16x8*)&Wo_l[(w * 16 + l15) * 64 + quad * 8];
            f16x8 wb1 = *(const f16x8*)&Wo_l[(w * 16 + l15) * 64 + 32 + quad * 8];
            float bov = bo_l[w * 16 + l15];
            floatx4 oacc[MT];
#pragma unroll
            for (int m = 0; m < MT; ++m) {
                oacc[m] = {0.f, 0.f, 0.f, 0.f};
                oacc[m] = MFMA(aa[m][0], wb0, oacc[m]);
                oacc[m] = MFMA(aa[m][1], wb1, oacc[m]);
            }
            int col = w * 16 + l15;
#pragma unroll
            for (int m = 0; m < MT; ++m)
#pragma unroll
                for (int r = 0; r < 4; ++r) {
                    int row = m * 16 + quad * 4 + r;
                    vbuf[row * XS + col] = (f16)(oacc[m][r] + bov + (float)xlds[row * XS + col]);
                }
        }
        __syncthreads();

        // ===== LN1: y(vbuf) -> x =====
        if (tid < G * S) ln_row(&vbuf[tid * XS], &xlds[tid * XS], ln1g_l, ln1b_l);
        __syncthreads();

        // ===== FF: 4 chunks of 128, W2 accumulators persistent; h overlays q|k =====
        {
            f16x8 a2[MT][2];
#pragma unroll
            for (int m = 0; m < MT; ++m)
#pragma unroll
                for (int kf = 0; kf < 2; ++kf)
                    a2[m][kf] = *(const f16x8*)&xlds[(m * 16 + l15) * XS + kf * 32 + quad * 8];
            floatx4 facc[MT];
#pragma unroll
            for (int m = 0; m < MT; ++m) facc[m] = {0.f, 0.f, 0.f, 0.f};

#pragma unroll 1
            for (int c = 0; c < 4; ++c) {
                // h = gelu(x @ W1_chunk^T + b1)
#pragma unroll
                for (int ntl = w; ntl < 8; ntl += 4) {
                    int gc = c * 128 + ntl * 16 + l15;
                    f16x8 w1b0 = *(const f16x8*)&W1_l[gc * 64 + quad * 8];
                    f16x8 w1b1 = *(const f16x8*)&W1_l[gc * 64 + 32 + quad * 8];
                    float b1v = b1_l[gc];
                    floatx4 hacc[MT];
#pragma unroll
                    for (int m = 0; m < MT; ++m) {
                        hacc[m] = {0.f, 0.f, 0.f, 0.f};
                        hacc[m] = MFMA(a2[m][0], w1b0, hacc[m]);
                        hacc[m] = MFMA(a2[m][1], w1b1, hacc[m]);
                    }
#pragma unroll
                    for (int m = 0; m < MT; ++m)
#pragma unroll
                        for (int r = 0; r < 4; ++r) {
                            int row = m * 16 + quad * 4 + r;
                            hbuf[row * HS + ntl * 16 + l15] = (f16)gelu_f(hacc[m][r] + b1v);
                        }
                }
                __syncthreads();
                // facc += h_chunk @ W2_chunk^T
                f16x8 w2b[4];
#pragma unroll
                for (int kf = 0; kf < 4; ++kf)
                    w2b[kf] = *(const f16x8*)&W2_l[(w * 16 + l15) * 512 + c * 128 + kf * 32 + quad * 8];
#pragma unroll
                for (int m = 0; m < MT; ++m) {
                    f16x8 ah0 = *(const f16x8*)&hbuf[(m * 16 + l15) * HS + 0 + quad * 8];
                    f16x8 ah1 = *(const f16x8*)&hbuf[(m * 16 + l15) * HS + 32 + quad * 8];
                    f16x8 ah2 = *(const f16x8*)&hbuf[(m * 16 + l15) * HS + 64 + quad * 8];
                    f16x8 ah3 = *(const f16x8*)&hbuf[(m * 16 + l15) * HS + 96 + quad * 8];
                    facc[m] = MFMA(ah0, w2b[0], facc[m]);
                    facc[m] = MFMA(ah1, w2b[1], facc[m]);
                    facc[m] = MFMA(ah2, w2b[2], facc[m]);
                    facc[m] = MFMA(ah3, w2b[3], facc[m]);
                }
                __syncthreads();
            }

            // y2 = ff + b2 + x  -> vbuf (y dead after LN1)
            float b2v = b2_l[w * 16 + l15];
            int col = w * 16 + l15;
#pragma unroll
            for (int m = 0; m < MT; ++m)
#pragma unroll
                for (int r = 0; r < 4; ++r) {
                    int row = m * 16 + quad * 4 + r;
                    vbuf[row * XS + col] = (f16)(facc[m][r] + b2v + (float)xlds[row * XS + col]);
                }
        }
        __syncthreads();

        // ===== LN2: y2(vbuf) -> x =====
        if (tid < G * S) ln_row(&vbuf[tid * XS], &xlds[tid * XS], ln2g_l, ln2b_l);
        __syncthreads();
    }

    // ---------- head: situation = ln(x[:,0] @ outW^T + outb) ----------
    {
        int i = tid >> 7, j = tid & 127;
        const f16* xr = &xlds[(i * S) * XS];
        float s = p.outb[j];
#pragma unroll
        for (int kv = 0; kv < 8; ++kv) {
            f16x8 xv = *(const f16x8*)&xr[kv * 8];
            floatx4 w0 = *(const floatx4*)&p.outW[j * 64 + kv * 8];
            floatx4 w1 = *(const floatx4*)&p.outW[j * 64 + kv * 8 + 4];
#pragma unroll
            for (int e = 0; e < 4; ++e) s += (float)xv[e] * w0[e];
#pragma unroll
            for (int e = 0; e < 4; ++e) s += (float)xv[4 + e] * w1[e];
        }
        sitlds[i * 128 + j] = s;
    }
    __syncthreads();

    // situation layernorm (wave 0 -> item 0, wave 1 -> item 1)
    if (w < 2) {
        int i = w;
        float v0 = sitlds[i * 128 + lane];
        float v1 = sitlds[i * 128 + 64 + lane];
        float sum = v0 + v1, sq = v0 * v0 + v1 * v1;
#pragma unroll
        for (int off = 32; off >= 1; off >>= 1) {
            sum += __shfl_xor(sum, off, 64);
            sq += __shfl_xor(sq, off, 64);
        }
        float mean = sum * (1.f / 128.f);
        float rs = rsqrtf(sq * (1.f / 128.f) - mean * mean + 1e-5f);
        int b = b0 + i;
        __builtin_nontemporal_store((v0 - mean) * rs * p.olng[lane] + p.olnb[lane],
                                    &p.out[b * 128 + lane]);
        __builtin_nontemporal_store((v1 - mean) * rs * p.olng[64 + lane] + p.olnb[64 + lane],
                                    &p.out[b * 128 + 64 + lane]);
    }

    // situation_sequence: x rows 1..24 -> fp32 (nontemporal: keep L2 for weights)
    for (int pp = tid; pp < G * 384; pp += 256) {  // 384 = 24*64/4
        int i = pp / 384;
        int q = pp - i * 384;
        int s = q >> 4, dp = (q & 15) * 4;
        int b = b0 + i;
        f16x4 xv = *(const f16x4*)&xlds[(i * S + 1 + s) * XS + dp];
        floatx4 o = {(float)xv[0], (float)xv[1], (float)xv[2], (float)xv[3]};
        __builtin_nontemporal_store(o, (floatx4*)&p.out[SEQOFF + b * 1536 + s * 64 + dp]);
    }
    // new_memory rows 0..8: passthrough of memory_context rows 1..9 (fp32)
    for (int pp = tid; pp < G * 144; pp += 256) {  // 144 = 9*64/4
        int i = pp / 144;
        int q = pp - i * 144;
        int mr = q >> 4, dp = (q & 15) * 4;
        int b = b0 + i;
        floatx4 v = *(const floatx4*)&p.mem[b * 640 + (1 + mr) * 64 + dp];
        __builtin_nontemporal_store(v, (floatx4*)&p.out[MEMOFF + b * 640 + mr * 64 + dp]);
    }
    // new_memory row 9: mean of x rows 1..24
    if (tid < G * 64) {
        int i = tid >> 6, d = tid & 63;
        float s = 0.f;
#pragma unroll
        for (int sr = 0; sr < 24; ++sr) s += (float)xlds[(i * S + 1 + sr) * XS + d];
        __builtin_nontemporal_store(s * (1.f / 24.f), &p.out[MEMOFF + (b0 + i) * 640 + 576 + d]);
    }
}

extern "C" void kernel_launch(void* const* d_in, const int* in_sizes, int n_in,
                              void* d_out, int out_size, void* d_ws, size_t ws_size,
                              hipStream_t stream) {
    (void)in_sizes; (void)n_in; (void)out_size; (void)ws_size;

    // weight conversion pre-pass: fp32 -> f16 into workspace (one kernel)
    f16* ws = (f16*)d_ws;
    hipLaunchKernelGGL(cvt_all, dim3(240), dim3(256), 0, stream,
                       (const float*)d_in[11], (const float*)d_in[13],
                       (const float*)d_in[17], (const float*)d_in[19], ws);

    Params p;
    p.tok = (const int*)d_in[0];
    p.traits = (const float*)d_in[1];
    p.relg = (const float*)d_in[2];
    p.mem = (const float*)d_in[3];
    p.temb = (const float*)d_in[4];
    p.demb = (const float*)d_in[5];
    p.traitW = (const float*)d_in[6];
    p.traitb = (const float*)d_in[7];
    p.intentW = (const float*)d_in[8];
    p.intentb = (const float*)d_in[9];
    p.cls = (const float*)d_in[10];
    p.bqkv = (const float*)d_in[12];
    p.bo = (const float*)d_in[14];
    p.ln1g = (const float*)d_in[15];
    p.ln1b = (const float*)d_in[16];
    p.b1 = (const float*)d_in[18];
    p.b2 = (const float*)d_in[20];
    p.ln2g = (const float*)d_in[21];
    p.ln2b = (const float*)d_in[22];
    p.outW = (const float*)d_in[23];
    p.outb = (const float*)d_in[24];
    p.olng = (const float*)d_in[25];
    p.olnb = (const float*)d_in[26];
    p.Wqkv = ws;                 // 36864
    p.Wo = ws + 36864;           // 12288
    p.W1 = ws + 49152;           // 98304
    p.W2 = ws + 147456;          // 98304
    p.out = (float*)d_out;

    hipLaunchKernelGGL(fused_tfm_kernel, dim3(4096 / G), dim3(256), 0, stream, p);
}

// Round 6
// 457.348 us; speedup vs baseline: 1.4006x; 1.1442x over previous
//
#include <hip/hip_runtime.h>

typedef _Float16 f16;
typedef _Float16 f16x2 __attribute__((ext_vector_type(2)));
typedef _Float16 f16x4 __attribute__((ext_vector_type(4)));
typedef _Float16 f16x8 __attribute__((ext_vector_type(8)));
typedef float floatx4 __attribute__((ext_vector_type(4)));

#define MFMA(a, b, c) __builtin_amdgcn_mfma_f32_16x16x32_f16((a), (b), (c), 0, 0, 0)

// Problem constants
constexpr int S = 35;        // 1 cls + 24 dims + 10 mem
constexpr int NH = 8;
constexpr int NL = 3;
constexpr int G = 2;         // batch items per block
constexpr int RP = 80;       // padded rows (G*35 = 70 -> 5 row-tiles)
constexpr int MT = 5;        // MFMA row-tiles
constexpr int XS = 72;       // row stride for 64-col buffers (144B rows -> 2-way banks, free)
constexpr int HS = 136;      // ff-chunk LDS stride (chunk 128)
constexpr int BUF = RP * XS; // 5760 elems per 80x64 buffer
constexpr int SEQOFF = 4096 * 128;                 // 524288
constexpr int MEMOFF = SEQOFF + 4096 * 24 * 64;    // 6815744

struct Params {
    const int* tok;
    // fp32 inputs
    const float *traits, *relg, *mem, *temb, *demb, *traitW, *traitb, *intentW, *intentb, *cls;
    const float *bqkv, *bo, *ln1g, *ln1b, *b1, *b2, *ln2g, *ln2b;
    const float *outW, *outb, *olng, *olnb;
    // f16 weights (converted into d_ws by pre-pass)
    const f16 *Wqkv, *Wo, *W1, *W2;
    float* out;
};

// single merged fp32->f16 conversion for all 4 weight tensors
__global__ void cvt_all(const float* __restrict__ wqkv, const float* __restrict__ wo,
                        const float* __restrict__ w1, const float* __restrict__ w2,
                        f16* __restrict__ dst) {
    int i = (blockIdx.x * 256 + threadIdx.x) * 4;
    const float* src;
    int off;
    if (i < 36864)       { src = wqkv; off = 0; }
    else if (i < 49152)  { src = wo;   off = 36864; }
    else if (i < 147456) { src = w1;   off = 49152; }
    else                 { src = w2;   off = 147456; }
    floatx4 v = *(const floatx4*)&src[i - off];
    f16x4 o;
    o[0] = (f16)v[0]; o[1] = (f16)v[1]; o[2] = (f16)v[2]; o[3] = (f16)v[3];
    *(f16x4*)&dst[i] = o;
}

__device__ inline f16x4 pack4(float a, float b, float c, float d) {
    f16x2 lo = __builtin_bit_cast(f16x2, __builtin_amdgcn_cvt_pkrtz(a, b));
    f16x2 hi = __builtin_bit_cast(f16x2, __builtin_amdgcn_cvt_pkrtz(c, d));
    f16x4 r; r[0] = lo[0]; r[1] = lo[1]; r[2] = hi[0]; r[3] = hi[1];
    return r;
}

__device__ inline float gelu_f(float x) {
    // tanh-form gelu via sigmoid; rcp instead of exact divide; max dev ~3e-4
    float x3 = x * x * x;
    float y = 1.5957691216f * (x + 0.044715f * x3);
    float z = __expf(-y);
    return x * __builtin_amdgcn_rcpf(1.f + z);
}

__device__ inline void ln_row(const f16* src, f16* dst, const float* g, const float* bb) {
    float v[64];
    float sum = 0.f, sq = 0.f;
#pragma unroll
    for (int kv = 0; kv < 8; ++kv) {
        f16x8 x8 = *(const f16x8*)&src[kv * 8];
#pragma unroll
        for (int e = 0; e < 8; ++e) {
            float f = (float)x8[e];
            v[kv * 8 + e] = f;
            sum += f;
            sq += f * f;
        }
    }
    float mean = sum * (1.f / 64.f);
    float var = sq * (1.f / 64.f) - mean * mean;
    float rs = rsqrtf(var + 1e-5f);
#pragma unroll
    for (int kv = 0; kv < 16; ++kv) {
        floatx4 g4 = *(const floatx4*)&g[kv * 4];
        floatx4 b4 = *(const floatx4*)&bb[kv * 4];
        *(f16x4*)&dst[kv * 4] = pack4((v[kv * 4 + 0] - mean) * rs * g4[0] + b4[0],
                                      (v[kv * 4 + 1] - mean) * rs * g4[1] + b4[1],
                                      (v[kv * 4 + 2] - mean) * rs * g4[2] + b4[2],
                                      (v[kv * 4 + 3] - mean) * rs * g4[3] + b4[3]);
    }
}

__global__ __launch_bounds__(256, 3) void fused_tfm_kernel(Params p) {
    // LDS budget: 11520 + 34560 + 1024 = 47104 B -> 3 blocks/CU
    __shared__ __align__(16) f16 xlds[BUF];          // x (residual stream)
    __shared__ __align__(16) f16 scratch[3 * BUF];   // q|k|v, then h / y / y2
    __shared__ float sitlds[G * 128];

    f16* qbuf = scratch;
    f16* kbuf = scratch + BUF;
    f16* vbuf = scratch + 2 * BUF;       // also y / y2 home
    f16* hbuf = scratch;                 // FF h-chunk: 80*136 elems, overlays dead q|k

    const int tid = threadIdx.x;
    const int lane = tid & 63;
    const int w = tid >> 6;
    const int l15 = lane & 15;
    const int quad = lane >> 4;
    const int b0 = blockIdx.x * G;

    // ---------- phase 0a: token+pos embedding into scratch ----------
    float* tokpos = (float*)scratch;
    for (int idx = tid; idx < 24 * 64; idx += 256) {
        int s = idx >> 6, d = idx & 63;
        float a = 0.f;
#pragma unroll
        for (int t = 0; t < 8; ++t) a += p.temb[p.tok[s * 8 + t] * 64 + d];
        tokpos[idx] = a * 0.125f + p.demb[idx] + p.traitb[d] + p.intentb[d];
    }
    __syncthreads();

    // ---------- phase 0b: build x in LDS (f16) ----------
    for (int idx = tid; idx < G * S * 64; idx += 256) {
        int i = idx / (S * 64);
        int rem = idx - i * S * 64;
        int r = rem >> 6, d = rem & 63;
        int b = b0 + i;
        float v;
        if (r == 0) {
            v = p.cls[d];
        } else if (r <= 24) {
            int s = r - 1;
            v = tokpos[s * 64 + d] + p.traits[b * 48 + s * 2] * p.traitW[d * 2]
                + p.traits[b * 48 + s * 2 + 1] * p.traitW[d * 2 + 1]
                + p.relg[b * 24 + s] * p.intentW[d];
        } else {
            v = p.mem[b * 640 + (r - 25) * 64 + d];
        }
        xlds[(i * S + r) * XS + d] = (f16)v;
    }
    for (int idx = tid; idx < (RP - G * S) * 64; idx += 256) {
        int r = G * S + (idx >> 6), d = idx & 63;
        xlds[r * XS + d] = (f16)0.f;
    }
    __syncthreads();

    // ---------- layers ----------
#pragma unroll 1
    for (int l = 0; l < NL; ++l) {
        const f16* Wqkv_l = p.Wqkv + l * 192 * 64;
        const float* bqkv_l = p.bqkv + l * 192;
        const f16* Wo_l = p.Wo + l * 64 * 64;
        const float* bo_l = p.bo + l * 64;
        const float* ln1g_l = p.ln1g + l * 64;
        const float* ln1b_l = p.ln1b + l * 64;
        const f16* W1_l = p.W1 + l * 512 * 64;
        const float* b1_l = p.b1 + l * 512;
        const f16* W2_l = p.W2 + l * 64 * 512;
        const float* b2_l = p.b2 + l * 64;
        const float* ln2g_l = p.ln2g + l * 64;
        const float* ln2b_l = p.ln2b + l * 64;

        // ===== QKV GEMM (swapped: D^T) -> q|k|v, token-row-major packed stores =====
        {
            f16x8 xb[MT][2];   // x token-rows as B-operand
#pragma unroll
            for (int m = 0; m < MT; ++m)
#pragma unroll
                for (int kf = 0; kf < 2; ++kf)
                    xb[m][kf] = *(const f16x8*)&xlds[(m * 16 + l15) * XS + kf * 32 + quad * 8];
#pragma unroll
            for (int nt = w; nt < 12; nt += 4) {
                f16x8 wf0 = *(const f16x8*)&Wqkv_l[(nt * 16 + l15) * 64 + quad * 8];
                f16x8 wf1 = *(const f16x8*)&Wqkv_l[(nt * 16 + l15) * 64 + 32 + quad * 8];
                floatx4 bias4 = *(const floatx4*)&bqkv_l[nt * 16 + quad * 4];
                f16* dst = scratch + (nt >> 2) * BUF;
                int oc = (nt & 3) * 16 + quad * 4;
                floatx4 acc[MT];
#pragma unroll
                for (int m = 0; m < MT; ++m) {
                    acc[m] = {0.f, 0.f, 0.f, 0.f};
                    acc[m] = MFMA(wf0, xb[m][0], acc[m]);
                    acc[m] = MFMA(wf1, xb[m][1], acc[m]);
                }
#pragma unroll
                for (int m = 0; m < MT; ++m) {
                    int row = m * 16 + l15;
                    *(f16x4*)&dst[row * XS + oc] =
                        pack4(acc[m][0] + bias4[0], acc[m][1] + bias4[1],
                              acc[m][2] + bias4[2], acc[m][3] + bias4[3]);
                }
            }
        }
        __syncthreads();

        // ===== attention (packed f16 VALU); output IN PLACE into q slot =====
        for (int t = tid; t < G * NH * S; t += 256) {
            int i = t / (NH * S);
            int rem = t - i * (NH * S);
            int h = rem / S;
            int q = rem - h * S;
            int rbase = i * S;
            const f16x2* qp = (const f16x2*)&qbuf[(rbase + q) * XS + h * 8];
            f16x2 q0 = qp[0], q1 = qp[1], q2 = qp[2], q3 = qp[3];
            float sc[S];
            float mx = -1e30f;
#pragma unroll
            for (int j = 0; j < S; ++j) {
                const f16x2* kp = (const f16x2*)&kbuf[(rbase + j) * XS + h * 8];
                f16x2 acc2 = q0 * kp[0];
                acc2 = q1 * kp[1] + acc2;
                acc2 = q2 * kp[2] + acc2;
                acc2 = q3 * kp[3] + acc2;
                float s = ((float)acc2[0] + (float)acc2[1]) * 0.35355339059f;
                sc[j] = s;
                mx = fmaxf(mx, s);
            }
            float lsum = 0.f;
#pragma unroll
            for (int j = 0; j < S; ++j) {
                sc[j] = __expf(sc[j] - mx);
                lsum += sc[j];
            }
            f16x2 o0 = {0.f, 0.f}, o1 = {0.f, 0.f}, o2 = {0.f, 0.f}, o3 = {0.f, 0.f};
#pragma unroll
            for (int j = 0; j < S; ++j) {
                const f16x2* vp = (const f16x2*)&vbuf[(rbase + j) * XS + h * 8];
                f16 sj = (f16)sc[j];
                f16x2 s2 = {sj, sj};
                o0 = vp[0] * s2 + o0;
                o1 = vp[1] * s2 + o1;
                o2 = vp[2] * s2 + o2;
                o3 = vp[3] * s2 + o3;
            }
            f16 invh = (f16)__builtin_amdgcn_rcpf(lsum);
            f16x2 inv2 = {invh, invh};
            o0 *= inv2; o1 *= inv2; o2 *= inv2; o3 *= inv2;
            f16x8 ov;
            ov[0] = o0[0]; ov[1] = o0[1]; ov[2] = o1[0]; ov[3] = o1[1];
            ov[4] = o2[0]; ov[5] = o2[1]; ov[6] = o3[0]; ov[7] = o3[1];
            *(f16x8*)&qbuf[(rbase + q) * XS + h * 8] = ov;
        }
        __syncthreads();

        // ===== Wo GEMM (swapped) + residual -> y in vbuf =====
        {
            f16x8 ab[MT][2];   // attn token-rows as B-operand
#pragma unroll
            for (int m = 0; m < MT; ++m)
#pragma unroll
                for (int kf = 0; kf < 2; ++kf)
                    ab[m][kf] = *(const f16x8*)&qbuf[(m * 16 + l15) * XS + kf * 32 + quad * 8];
            f16x8 wf0 = *(const f16x8*)&Wo_l[(w * 16 + l15) * 64 + quad * 8];
            f16x8 wf1 = *(const f16x8*)&Wo_l[(w * 16 + l15) * 64 + 32 + quad * 8];
            int oc = w * 16 + quad * 4;
            floatx4 bo4 = *(const floatx4*)&bo_l[oc];
            floatx4 oacc[MT];
#pragma unroll
            for (int m = 0; m < MT; ++m) {
                oacc[m] = {0.f, 0.f, 0.f, 0.f};
                oacc[m] = MFMA(wf0, ab[m][0], oacc[m]);
                oacc[m] = MFMA(wf1, ab[m][1], oacc[m]);
            }
#pragma unroll
            for (int m = 0; m < MT; ++m) {
                int row = m * 16 + l15;
                f16x4 res = *(const f16x4*)&xlds[row * XS + oc];
                *(f16x4*)&vbuf[row * XS + oc] =
                    pack4(oacc[m][0] + bo4[0] + (float)res[0],
                          oacc[m][1] + bo4[1] + (float)res[1],
                          oacc[m][2] + bo4[2] + (float)res[2],
                          oacc[m][3] + bo4[3] + (float)res[3]);
            }
        }
        __syncthreads();

        // ===== LN1: y(vbuf) -> x =====
        if (tid < G * S) ln_row(&vbuf[tid * XS], &xlds[tid * XS], ln1g_l, ln1b_l);
        __syncthreads();

        // ===== FF: 4 chunks of 128 (swapped GEMMs), W2 accumulators persistent =====
        {
            f16x8 a2[MT][2];   // x token-rows as B-operand
#pragma unroll
            for (int m = 0; m < MT; ++m)
#pragma unroll
                for (int kf = 0; kf < 2; ++kf)
                    a2[m][kf] = *(const f16x8*)&xlds[(m * 16 + l15) * XS + kf * 32 + quad * 8];
            floatx4 facc[MT];
#pragma unroll
            for (int m = 0; m < MT; ++m) facc[m] = {0.f, 0.f, 0.f, 0.f};

#pragma unroll 1
            for (int c = 0; c < 4; ++c) {
                // h = gelu(x @ W1_chunk^T + b1), token-row-major in hbuf
#pragma unroll
                for (int ntl = w; ntl < 8; ntl += 4) {
                    int gc = c * 128 + ntl * 16;
                    f16x8 w1f0 = *(const f16x8*)&W1_l[(gc + l15) * 64 + quad * 8];
                    f16x8 w1f1 = *(const f16x8*)&W1_l[(gc + l15) * 64 + 32 + quad * 8];
                    floatx4 b14 = *(const floatx4*)&b1_l[gc + quad * 4];
                    int oc = ntl * 16 + quad * 4;
                    floatx4 hacc[MT];
#pragma unroll
                    for (int m = 0; m < MT; ++m) {
                        hacc[m] = {0.f, 0.f, 0.f, 0.f};
                        hacc[m] = MFMA(w1f0, a2[m][0], hacc[m]);
                        hacc[m] = MFMA(w1f1, a2[m][1], hacc[m]);
                    }
#pragma unroll
                    for (int m = 0; m < MT; ++m) {
                        int row = m * 16 + l15;
                        *(f16x4*)&hbuf[row * HS + oc] =
                            pack4(gelu_f(hacc[m][0] + b14[0]), gelu_f(hacc[m][1] + b14[1]),
                                  gelu_f(hacc[m][2] + b14[2]), gelu_f(hacc[m][3] + b14[3]));
                    }
                }
                __syncthreads();
                // facc += W2_chunk @ h^T  (swapped)
                f16x8 w2f[4];
#pragma unroll
                for (int kf = 0; kf < 4; ++kf)
                    w2f[kf] = *(const f16x8*)&W2_l[(w * 16 + l15) * 512 + c * 128 + kf * 32 + quad * 8];
#pragma unroll
                for (int m = 0; m < MT; ++m) {
                    f16x8 h0 = *(const f16x8*)&hbuf[(m * 16 + l15) * HS + 0 + quad * 8];
                    f16x8 h1 = *(const f16x8*)&hbuf[(m * 16 + l15) * HS + 32 + quad * 8];
                    f16x8 h2 = *(const f16x8*)&hbuf[(m * 16 + l15) * HS + 64 + quad * 8];
                    f16x8 h3 = *(const f16x8*)&hbuf[(m * 16 + l15) * HS + 96 + quad * 8];
                    facc[m] = MFMA(w2f[0], h0, facc[m]);
                    facc[m] = MFMA(w2f[1], h1, facc[m]);
                    facc[m] = MFMA(w2f[2], h2, facc[m]);
                    facc[m] = MFMA(w2f[3], h3, facc[m]);
                }
                __syncthreads();
            }

            // y2 = ff + b2 + x -> vbuf
            int oc = w * 16 + quad * 4;
            floatx4 b24 = *(const floatx4*)&b2_l[oc];
#pragma unroll
            for (int m = 0; m < MT; ++m) {
                int row = m * 16 + l15;
                f16x4 res = *(const f16x4*)&xlds[row * XS + oc];
                *(f16x4*)&vbuf[row * XS + oc] =
                    pack4(facc[m][0] + b24[0] + (float)res[0],
                          facc[m][1] + b24[1] + (float)res[1],
                          facc[m][2] + b24[2] + (float)res[2],
                          facc[m][3] + b24[3] + (float)res[3]);
            }
        }
        __syncthreads();

        // ===== LN2: y2(vbuf) -> x =====
        if (tid < G * S) ln_row(&vbuf[tid * XS], &xlds[tid * XS], ln2g_l, ln2b_l);
        __syncthreads();
    }

    // ---------- head: situation = ln(x[:,0] @ outW^T + outb) ----------
    {
        int i = tid >> 7, j = tid & 127;
        const f16* xr = &xlds[(i * S) * XS];
        float s = p.outb[j];
#pragma unroll
        for (int kv = 0; kv < 8; ++kv) {
            f16x8 xv = *(const f16x8*)&xr[kv * 8];
            floatx4 w0 = *(const floatx4*)&p.outW[j * 64 + kv * 8];
            floatx4 w1 = *(const floatx4*)&p.outW[j * 64 + kv * 8 + 4];
#pragma unroll
            for (int e = 0; e < 4; ++e) s += (float)xv[e] * w0[e];
#pragma unroll
            for (int e = 0; e < 4; ++e) s += (float)xv[4 + e] * w1[e];
        }
        sitlds[i * 128 + j] = s;
    }
    __syncthreads();

    if (w < 2) {
        int i = w;
        float v0 = sitlds[i * 128 + lane];
        float v1 = sitlds[i * 128 + 64 + lane];
        float sum = v0 + v1, sq = v0 * v0 + v1 * v1;
#pragma unroll
        for (int off = 32; off >= 1; off >>= 1) {
            sum += __shfl_xor(sum, off, 64);
            sq += __shfl_xor(sq, off, 64);
        }
        float mean = sum * (1.f / 128.f);
        float rs = rsqrtf(sq * (1.f / 128.f) - mean * mean + 1e-5f);
        int b = b0 + i;
        __builtin_nontemporal_store((v0 - mean) * rs * p.olng[lane] + p.olnb[lane],
                                    &p.out[b * 128 + lane]);
        __builtin_nontemporal_store((v1 - mean) * rs * p.olng[64 + lane] + p.olnb[64 + lane],
                                    &p.out[b * 128 + 64 + lane]);
    }

    // situation_sequence: x rows 1..24 -> fp32
    for (int pp = tid; pp < G * 384; pp += 256) {
        int i = pp / 384;
        int q = pp - i * 384;
        int s = q >> 4, dp = (q & 15) * 4;
        int b = b0 + i;
        f16x4 xv = *(const f16x4*)&xlds[(i * S + 1 + s) * XS + dp];
        floatx4 o = {(float)xv[0], (float)xv[1], (float)xv[2], (float)xv[3]};
        __builtin_nontemporal_store(o, (floatx4*)&p.out[SEQOFF + b * 1536 + s * 64 + dp]);
    }
    // new_memory rows 0..8: passthrough of memory_context rows 1..9
    for (int pp = tid; pp < G * 144; pp += 256) {
        int i = pp / 144;
        int q = pp - i * 144;
        int mr = q >> 4, dp = (q & 15) * 4;
        int b = b0 + i;
        floatx4 v = *(const floatx4*)&p.mem[b * 640 + (1 + mr) * 64 + dp];
        __builtin_nontemporal_store(v, (floatx4*)&p.out[MEMOFF + b * 640 + mr * 64 + dp]);
    }
    // new_memory row 9: mean of x rows 1..24
    if (tid < G * 64) {
        int i = tid >> 6, d = tid & 63;
        float s = 0.f;
#pragma unroll
        for (int sr = 0; sr < 24; ++sr) s += (float)xlds[(i * S + 1 + sr) * XS + d];
        __builtin_nontemporal_store(s * (1.f / 24.f), &p.out[MEMOFF + (b0 + i) * 640 + 576 + d]);
    }
}

extern "C" void kernel_launch(void* const* d_in, const int* in_sizes, int n_in,
                              void* d_out, int out_size, void* d_ws, size_t ws_size,
                              hipStream_t stream) {
    (void)in_sizes; (void)n_in; (void)out_size; (void)ws_size;

    f16* ws = (f16*)d_ws;
    hipLaunchKernelGGL(cvt_all, dim3(240), dim3(256), 0, stream,
                       (const float*)d_in[11], (const float*)d_in[13],
                       (const float*)d_in[17], (const float*)d_in[19], ws);

    Params p;
    p.tok = (const int*)d_in[0];
    p.traits = (const float*)d_in[1];
    p.relg = (const float*)d_in[2];
    p.mem = (const float*)d_in[3];
    p.temb = (const float*)d_in[4];
    p.demb = (const float*)d_in[5];
    p.traitW = (const float*)d_in[6];
    p.traitb = (const float*)d_in[7];
    p.intentW = (const float*)d_in[8];
    p.intentb = (const float*)d_in[9];
    p.cls = (const float*)d_in[10];
    p.bqkv = (const float*)d_in[12];
    p.bo = (const float*)d_in[14];
    p.ln1g = (const float*)d_in[15];
    p.ln1b = (const float*)d_in[16];
    p.b1 = (const float*)d_in[18];
    p.b2 = (const float*)d_in[20];
    p.ln2g = (const float*)d_in[21];
    p.ln2b = (const float*)d_in[22];
    p.outW = (const float*)d_in[23];
    p.outb = (const float*)d_in[24];
    p.olng = (const float*)d_in[25];
    p.olnb = (const float*)d_in[26];
    p.Wqkv = ws;                 // 36864
    p.Wo = ws + 36864;           // 12288
    p.W1 = ws + 49152;           // 98304
    p.W2 = ws + 147456;          // 98304
    p.out = (float*)d_out;

    hipLaunchKernelGGL(fused_tfm_kernel, dim3(4096 / G), dim3(256), 0, stream, p);
}

// Round 7
// 431.724 us; speedup vs baseline: 1.4838x; 1.0594x over previous
//
#include <hip/hip_runtime.h>

typedef _Float16 f16;
typedef _Float16 f16x2 __attribute__((ext_vector_type(2)));
typedef _Float16 f16x4 __attribute__((ext_vector_type(4)));
typedef _Float16 f16x8 __attribute__((ext_vector_type(8)));
typedef float floatx4 __attribute__((ext_vector_type(4)));

#define MFMA(a, b, c) __builtin_amdgcn_mfma_f32_16x16x32_f16((a), (b), (c), 0, 0, 0)

// Problem constants
constexpr int S = 35;        // 1 cls + 24 dims + 10 mem
constexpr int NH = 8;
constexpr int NL = 3;
constexpr int G = 2;         // batch items per block
constexpr int RP = 80;       // padded rows (G*35 = 70 -> 5 row-tiles)
constexpr int MT = 5;        // MFMA row-tiles
constexpr int BUF = RP * 64; // 5120 elems per swizzled 80x64 buffer
constexpr int SEQOFF = 4096 * 128;                 // 524288
constexpr int MEMOFF = SEQOFF + 4096 * 24 * 64;    // 6815744
constexpr int TOKPOS_OFF = 245760;                 // f16 elems into ws; tokpos floats live there

// XOR swizzle: 8-col groups rotated by row&7 -> stride-64 rows, conflict-free patterns
__device__ __forceinline__ int sw64(int r, int c) {
    return (r << 6) + ((((c >> 3) ^ r) & 7) << 3) + (c & 7);
}
__device__ __forceinline__ int sw128(int r, int c) {
    return (r << 7) + ((((c >> 3) ^ (r & 7))) << 3) + (c & 7);
}

struct Params {
    const int* tok;
    const float *traits, *relg, *mem, *temb, *demb, *traitW, *traitb, *intentW, *intentb, *cls;
    const float *bqkv, *bo, *ln1g, *ln1b, *b1, *b2, *ln2g, *ln2b;
    const float *outW, *outb, *olng, *olnb;
    const f16 *Wqkv, *Wo, *W1, *W2;   // converted into d_ws
    const float* tokpos;              // precomputed in d_ws
    float* out;
};

// fp32->f16 weight conversion + tokpos precompute (block 240)
__global__ void cvt_all(const float* __restrict__ wqkv, const float* __restrict__ wo,
                        const float* __restrict__ w1, const float* __restrict__ w2,
                        const int* __restrict__ tok, const float* __restrict__ temb,
                        const float* __restrict__ demb, const float* __restrict__ traitb,
                        const float* __restrict__ intentb, f16* __restrict__ dst) {
    if (blockIdx.x == 240) {
        // tokpos[s][d] = mean_t temb[tok[s,t]][d] + demb[s][d] + traitb[d] + intentb[d]
        float* tp = (float*)(dst + TOKPOS_OFF);
        for (int idx = threadIdx.x; idx < 24 * 64; idx += 256) {
            int s = idx >> 6, d = idx & 63;
            float a = 0.f;
#pragma unroll
            for (int t = 0; t < 8; ++t) a += temb[tok[s * 8 + t] * 64 + d];
            tp[idx] = a * 0.125f + demb[idx] + traitb[d] + intentb[d];
        }
        return;
    }
    int i = (blockIdx.x * 256 + threadIdx.x) * 4;
    const float* src;
    int off;
    if (i < 36864)       { src = wqkv; off = 0; }
    else if (i < 49152)  { src = wo;   off = 36864; }
    else if (i < 147456) { src = w1;   off = 49152; }
    else                 { src = w2;   off = 147456; }
    floatx4 v = *(const floatx4*)&src[i - off];
    f16x4 o;
    o[0] = (f16)v[0]; o[1] = (f16)v[1]; o[2] = (f16)v[2]; o[3] = (f16)v[3];
    *(f16x4*)&dst[i] = o;
}

__device__ inline f16x4 pack4(float a, float b, float c, float d) {
    f16x2 lo = __builtin_bit_cast(f16x2, __builtin_amdgcn_cvt_pkrtz(a, b));
    f16x2 hi = __builtin_bit_cast(f16x2, __builtin_amdgcn_cvt_pkrtz(c, d));
    f16x4 r; r[0] = lo[0]; r[1] = lo[1]; r[2] = hi[0]; r[3] = hi[1];
    return r;
}

__device__ inline float gelu_f(float x) {
    // tanh-form gelu in exp2 domain: sigmoid(1.5958*(x+0.044715x^3)); max dev ~3e-4
    float x2 = x * x;
    float u = __builtin_fmaf(x2, 0.044715f, 1.0f);
    float xm = x * -2.302585f;           // 1.5957691 * log2(e) folded
    float z = __builtin_amdgcn_exp2f(xm * u);
    return x * __builtin_amdgcn_rcpf(1.f + z);
}

__device__ inline void ln_row_sw(const f16* buf, f16* dst, int row, const float* g, const float* bb) {
    float v[64];
    float sum = 0.f, sq = 0.f;
#pragma unroll
    for (int kv = 0; kv < 8; ++kv) {
        f16x8 x8 = *(const f16x8*)&buf[sw64(row, kv * 8)];
#pragma unroll
        for (int e = 0; e < 8; ++e) {
            float f = (float)x8[e];
            v[kv * 8 + e] = f;
            sum += f;
            sq += f * f;
        }
    }
    float mean = sum * (1.f / 64.f);
    float var = sq * (1.f / 64.f) - mean * mean;
    float rs = rsqrtf(var + 1e-5f);
#pragma unroll
    for (int kv = 0; kv < 16; ++kv) {
        floatx4 g4 = *(const floatx4*)&g[kv * 4];
        floatx4 b4 = *(const floatx4*)&bb[kv * 4];
        *(f16x4*)&dst[sw64(row, kv * 4)] =
            pack4((v[kv * 4 + 0] - mean) * rs * g4[0] + b4[0],
                  (v[kv * 4 + 1] - mean) * rs * g4[1] + b4[1],
                  (v[kv * 4 + 2] - mean) * rs * g4[2] + b4[2],
                  (v[kv * 4 + 3] - mean) * rs * g4[3] + b4[3]);
    }
}

__global__ __launch_bounds__(256, 4) void fused_tfm_kernel(Params p) {
    // LDS: (5120 + 15360) f16 = 40960 B -> exactly 4 blocks/CU
    __shared__ __align__(16) f16 xlds[BUF];          // x (residual stream)
    __shared__ __align__(16) f16 scratch[3 * BUF];   // q|k|v, then h / y / y2; head reuses as float

    f16* qbuf = scratch;
    f16* kbuf = scratch + BUF;
    f16* vbuf = scratch + 2 * BUF;       // also y / y2 home
    f16* hbuf = scratch;                 // FF h-chunk: 80x128 swizzled, overlays dead q|k

    const int tid = threadIdx.x;
    const int lane = tid & 63;
    const int w = tid >> 6;
    const int l15 = lane & 15;
    const int quad = lane >> 4;
    const int b0 = blockIdx.x * G;

    // ---------- build x in LDS (f16, swizzled) ----------
    for (int idx = tid; idx < G * S * 64; idx += 256) {
        int i = idx / (S * 64);
        int rem = idx - i * S * 64;
        int r = rem >> 6, d = rem & 63;
        int b = b0 + i;
        float v;
        if (r == 0) {
            v = p.cls[d];
        } else if (r <= 24) {
            int s = r - 1;
            v = p.tokpos[s * 64 + d] + p.traits[b * 48 + s * 2] * p.traitW[d * 2]
                + p.traits[b * 48 + s * 2 + 1] * p.traitW[d * 2 + 1]
                + p.relg[b * 24 + s] * p.intentW[d];
        } else {
            v = p.mem[b * 640 + (r - 25) * 64 + d];
        }
        xlds[sw64(i * S + r, d)] = (f16)v;
    }
    for (int idx = tid; idx < (RP - G * S) * 64; idx += 256) {
        int r = G * S + (idx >> 6), d = idx & 63;
        xlds[sw64(r, d)] = (f16)0.f;
    }
    __syncthreads();

    // ---------- layers ----------
#pragma unroll 1
    for (int l = 0; l < NL; ++l) {
        const f16* Wqkv_l = p.Wqkv + l * 192 * 64;
        const float* bqkv_l = p.bqkv + l * 192;
        const f16* Wo_l = p.Wo + l * 64 * 64;
        const float* bo_l = p.bo + l * 64;
        const float* ln1g_l = p.ln1g + l * 64;
        const float* ln1b_l = p.ln1b + l * 64;
        const f16* W1_l = p.W1 + l * 512 * 64;
        const float* b1_l = p.b1 + l * 512;
        const f16* W2_l = p.W2 + l * 64 * 512;
        const float* b2_l = p.b2 + l * 64;
        const float* ln2g_l = p.ln2g + l * 64;
        const float* ln2b_l = p.ln2b + l * 64;

        // ===== QKV GEMM (swapped D^T) -> q|k|v, token-row-major packed stores =====
        {
            f16x8 xb[MT][2];
#pragma unroll
            for (int m = 0; m < MT; ++m)
#pragma unroll
                for (int kf = 0; kf < 2; ++kf)
                    xb[m][kf] = *(const f16x8*)&xlds[sw64(m * 16 + l15, kf * 32 + quad * 8)];
#pragma unroll
            for (int nt = w; nt < 12; nt += 4) {
                f16x8 wf0 = *(const f16x8*)&Wqkv_l[(nt * 16 + l15) * 64 + quad * 8];
                f16x8 wf1 = *(const f16x8*)&Wqkv_l[(nt * 16 + l15) * 64 + 32 + quad * 8];
                floatx4 bias4 = *(const floatx4*)&bqkv_l[nt * 16 + quad * 4];
                f16* dst = scratch + (nt >> 2) * BUF;
                int oc = (nt & 3) * 16 + quad * 4;
                floatx4 acc[MT];
#pragma unroll
                for (int m = 0; m < MT; ++m) {
                    acc[m] = {0.f, 0.f, 0.f, 0.f};
                    acc[m] = MFMA(wf0, xb[m][0], acc[m]);
                    acc[m] = MFMA(wf1, xb[m][1], acc[m]);
                }
#pragma unroll
                for (int m = 0; m < MT; ++m) {
                    int row = m * 16 + l15;
                    *(f16x4*)&dst[sw64(row, oc)] =
                        pack4(acc[m][0] + bias4[0], acc[m][1] + bias4[1],
                              acc[m][2] + bias4[2], acc[m][3] + bias4[3]);
                }
            }
        }
        __syncthreads();

        // ===== attention (packed f16 VALU, exp2-domain softmax); in-place into q =====
        for (int t = tid; t < G * NH * S; t += 256) {
            int i = t / (NH * S);
            int rem = t - i * (NH * S);
            int h = rem / S;
            int q = rem - h * S;
            int rbase = i * S;
            const f16x2* qp = (const f16x2*)&qbuf[sw64(rbase + q, h * 8)];
            f16x2 q0 = qp[0], q1 = qp[1], q2 = qp[2], q3 = qp[3];
            float sc[S];
            float mx = -1e30f;
#pragma unroll
            for (int j = 0; j < S; ++j) {
                const f16x2* kp = (const f16x2*)&kbuf[sw64(rbase + j, h * 8)];
                f16x2 acc2 = q0 * kp[0];
                acc2 = q1 * kp[1] + acc2;
                acc2 = q2 * kp[2] + acc2;
                acc2 = q3 * kp[3] + acc2;
                float s = ((float)acc2[0] + (float)acc2[1]) * 0.51006982f;  // 1/sqrt(8)*log2(e)
                sc[j] = s;
                mx = fmaxf(mx, s);
            }
            float lsum = 0.f;
#pragma unroll
            for (int j = 0; j < S; ++j) {
                sc[j] = __builtin_amdgcn_exp2f(sc[j] - mx);
                lsum += sc[j];
            }
            f16x2 o0 = {0.f, 0.f}, o1 = {0.f, 0.f}, o2 = {0.f, 0.f}, o3 = {0.f, 0.f};
#pragma unroll
            for (int j = 0; j < S; ++j) {
                const f16x2* vp = (const f16x2*)&vbuf[sw64(rbase + j, h * 8)];
                f16 sj = (f16)sc[j];
                f16x2 s2 = {sj, sj};
                o0 = vp[0] * s2 + o0;
                o1 = vp[1] * s2 + o1;
                o2 = vp[2] * s2 + o2;
                o3 = vp[3] * s2 + o3;
            }
            f16 invh = (f16)__builtin_amdgcn_rcpf(lsum);
            f16x2 inv2 = {invh, invh};
            o0 *= inv2; o1 *= inv2; o2 *= inv2; o3 *= inv2;
            f16x8 ov;
            ov[0] = o0[0]; ov[1] = o0[1]; ov[2] = o1[0]; ov[3] = o1[1];
            ov[4] = o2[0]; ov[5] = o2[1]; ov[6] = o3[0]; ov[7] = o3[1];
            *(f16x8*)&qbuf[sw64(rbase + q, h * 8)] = ov;
        }
        __syncthreads();

        // ===== Wo GEMM (swapped) + residual -> y in vbuf =====
        {
            f16x8 ab[MT][2];
#pragma unroll
            for (int m = 0; m < MT; ++m)
#pragma unroll
                for (int kf = 0; kf < 2; ++kf)
                    ab[m][kf] = *(const f16x8*)&qbuf[sw64(m * 16 + l15, kf * 32 + quad * 8)];
            f16x8 wf0 = *(const f16x8*)&Wo_l[(w * 16 + l15) * 64 + quad * 8];
            f16x8 wf1 = *(const f16x8*)&Wo_l[(w * 16 + l15) * 64 + 32 + quad * 8];
            int oc = w * 16 + quad * 4;
            floatx4 bo4 = *(const floatx4*)&bo_l[oc];
            floatx4 oacc[MT];
#pragma unroll
            for (int m = 0; m < MT; ++m) {
                oacc[m] = {0.f, 0.f, 0.f, 0.f};
                oacc[m] = MFMA(wf0, ab[m][0], oacc[m]);
                oacc[m] = MFMA(wf1, ab[m][1], oacc[m]);
            }
#pragma unroll
            for (int m = 0; m < MT; ++m) {
                int row = m * 16 + l15;
                f16x4 res = *(const f16x4*)&xlds[sw64(row, oc)];
                *(f16x4*)&vbuf[sw64(row, oc)] =
                    pack4(oacc[m][0] + bo4[0] + (float)res[0],
                          oacc[m][1] + bo4[1] + (float)res[1],
                          oacc[m][2] + bo4[2] + (float)res[2],
                          oacc[m][3] + bo4[3] + (float)res[3]);
            }
        }
        __syncthreads();

        // ===== LN1: y(vbuf) -> x =====
        if (tid < G * S) ln_row_sw(vbuf, xlds, tid, ln1g_l, ln1b_l);
        __syncthreads();

        // ===== FF: 4 chunks of 128 (swapped GEMMs), W2 accumulators persistent =====
        {
            f16x8 a2[MT][2];
#pragma unroll
            for (int m = 0; m < MT; ++m)
#pragma unroll
                for (int kf = 0; kf < 2; ++kf)
                    a2[m][kf] = *(const f16x8*)&xlds[sw64(m * 16 + l15, kf * 32 + quad * 8)];
            floatx4 facc[MT];
#pragma unroll
            for (int m = 0; m < MT; ++m) facc[m] = {0.f, 0.f, 0.f, 0.f};

#pragma unroll 1
            for (int c = 0; c < 4; ++c) {
#pragma unroll
                for (int ntl = w; ntl < 8; ntl += 4) {
                    int gc = c * 128 + ntl * 16;
                    f16x8 w1f0 = *(const f16x8*)&W1_l[(gc + l15) * 64 + quad * 8];
                    f16x8 w1f1 = *(const f16x8*)&W1_l[(gc + l15) * 64 + 32 + quad * 8];
                    floatx4 b14 = *(const floatx4*)&b1_l[gc + quad * 4];
                    int oc = ntl * 16 + quad * 4;
                    floatx4 hacc[MT];
#pragma unroll
                    for (int m = 0; m < MT; ++m) {
                        hacc[m] = {0.f, 0.f, 0.f, 0.f};
                        hacc[m] = MFMA(w1f0, a2[m][0], hacc[m]);
                        hacc[m] = MFMA(w1f1, a2[m][1], hacc[m]);
                    }
#pragma unroll
                    for (int m = 0; m < MT; ++m) {
                        int row = m * 16 + l15;
                        *(f16x4*)&hbuf[sw128(row, oc)] =
                            pack4(gelu_f(hacc[m][0] + b14[0]), gelu_f(hacc[m][1] + b14[1]),
                                  gelu_f(hacc[m][2] + b14[2]), gelu_f(hacc[m][3] + b14[3]));
                    }
                }
                __syncthreads();
                f16x8 w2f[4];
#pragma unroll
                for (int kf = 0; kf < 4; ++kf)
                    w2f[kf] = *(const f16x8*)&W2_l[(w * 16 + l15) * 512 + c * 128 + kf * 32 + quad * 8];
#pragma unroll
                for (int m = 0; m < MT; ++m) {
                    f16x8 h0 = *(const f16x8*)&hbuf[sw128(m * 16 + l15, 0 + quad * 8)];
                    f16x8 h1 = *(const f16x8*)&hbuf[sw128(m * 16 + l15, 32 + quad * 8)];
                    f16x8 h2 = *(const f16x8*)&hbuf[sw128(m * 16 + l15, 64 + quad * 8)];
                    f16x8 h3 = *(const f16x8*)&hbuf[sw128(m * 16 + l15, 96 + quad * 8)];
                    facc[m] = MFMA(w2f[0], h0, facc[m]);
                    facc[m] = MFMA(w2f[1], h1, facc[m]);
                    facc[m] = MFMA(w2f[2], h2, facc[m]);
                    facc[m] = MFMA(w2f[3], h3, facc[m]);
                }
                __syncthreads();
            }

            // y2 = ff + b2 + x -> vbuf
            int oc = w * 16 + quad * 4;
            floatx4 b24 = *(const floatx4*)&b2_l[oc];
#pragma unroll
            for (int m = 0; m < MT; ++m) {
                int row = m * 16 + l15;
                f16x4 res = *(const f16x4*)&xlds[sw64(row, oc)];
                *(f16x4*)&vbuf[sw64(row, oc)] =
                    pack4(facc[m][0] + b24[0] + (float)res[0],
                          facc[m][1] + b24[1] + (float)res[1],
                          facc[m][2] + b24[2] + (float)res[2],
                          facc[m][3] + b24[3] + (float)res[3]);
            }
        }
        __syncthreads();

        // ===== LN2: y2(vbuf) -> x =====
        if (tid < G * S) ln_row_sw(vbuf, xlds, tid, ln2g_l, ln2b_l);
        __syncthreads();
    }

    // ---------- head: situation = ln(x[:,0] @ outW^T + outb) ----------
    float* sitlds = (float*)scratch;  // scratch dead after last LN2 (barrier above)
    {
        int i = tid >> 7, j = tid & 127;
        float s = p.outb[j];
#pragma unroll
        for (int kv = 0; kv < 8; ++kv) {
            f16x8 xv = *(const f16x8*)&xlds[sw64(i * S, kv * 8)];
            floatx4 w0 = *(const floatx4*)&p.outW[j * 64 + kv * 8];
            floatx4 w1 = *(const floatx4*)&p.outW[j * 64 + kv * 8 + 4];
#pragma unroll
            for (int e = 0; e < 4; ++e) s += (float)xv[e] * w0[e];
#pragma unroll
            for (int e = 0; e < 4; ++e) s += (float)xv[4 + e] * w1[e];
        }
        sitlds[i * 128 + j] = s;
    }
    __syncthreads();

    if (w < 2) {
        int i = w;
        float v0 = sitlds[i * 128 + lane];
        float v1 = sitlds[i * 128 + 64 + lane];
        float sum = v0 + v1, sq = v0 * v0 + v1 * v1;
#pragma unroll
        for (int off = 32; off >= 1; off >>= 1) {
            sum += __shfl_xor(sum, off, 64);
            sq += __shfl_xor(sq, off, 64);
        }
        float mean = sum * (1.f / 128.f);
        float rs = rsqrtf(sq * (1.f / 128.f) - mean * mean + 1e-5f);
        int b = b0 + i;
        __builtin_nontemporal_store((v0 - mean) * rs * p.olng[lane] + p.olnb[lane],
                                    &p.out[b * 128 + lane]);
        __builtin_nontemporal_store((v1 - mean) * rs * p.olng[64 + lane] + p.olnb[64 + lane],
                                    &p.out[b * 128 + 64 + lane]);
    }

    // situation_sequence: x rows 1..24 -> fp32
    for (int pp = tid; pp < G * 384; pp += 256) {
        int i = pp / 384;
        int q = pp - i * 384;
        int s = q >> 4, dp = (q & 15) * 4;
        int b = b0 + i;
        f16x4 xv = *(const f16x4*)&xlds[sw64(i * S + 1 + s, dp)];
        floatx4 o = {(float)xv[0], (float)xv[1], (float)xv[2], (float)xv[3]};
        __builtin_nontemporal_store(o, (floatx4*)&p.out[SEQOFF + b * 1536 + s * 64 + dp]);
    }
    // new_memory rows 0..8: passthrough of memory_context rows 1..9
    for (int pp = tid; pp < G * 144; pp += 256) {
        int i = pp / 144;
        int q = pp - i * 144;
        int mr = q >> 4, dp = (q & 15) * 4;
        int b = b0 + i;
        floatx4 v = *(const floatx4*)&p.mem[b * 640 + (1 + mr) * 64 + dp];
        __builtin_nontemporal_store(v, (floatx4*)&p.out[MEMOFF + b * 640 + mr * 64 + dp]);
    }
    // new_memory row 9: mean of x rows 1..24
    if (tid < G * 64) {
        int i = tid >> 6, d = tid & 63;
        float s = 0.f;
#pragma unroll
        for (int sr = 0; sr < 24; ++sr) s += (float)xlds[sw64(i * S + 1 + sr, d)];
        __builtin_nontemporal_store(s * (1.f / 24.f), &p.out[MEMOFF + (b0 + i) * 640 + 576 + d]);
    }
}

extern "C" void kernel_launch(void* const* d_in, const int* in_sizes, int n_in,
                              void* d_out, int out_size, void* d_ws, size_t ws_size,
                              hipStream_t stream) {
    (void)in_sizes; (void)n_in; (void)out_size; (void)ws_size;

    f16* ws = (f16*)d_ws;
    hipLaunchKernelGGL(cvt_all, dim3(241), dim3(256), 0, stream,
                       (const float*)d_in[11], (const float*)d_in[13],
                       (const float*)d_in[17], (const float*)d_in[19],
                       (const int*)d_in[0], (const float*)d_in[4],
                       (const float*)d_in[5], (const float*)d_in[7],
                       (const float*)d_in[9], ws);

    Params p;
    p.tok = (const int*)d_in[0];
    p.traits = (const float*)d_in[1];
    p.relg = (const float*)d_in[2];
    p.mem = (const float*)d_in[3];
    p.temb = (const float*)d_in[4];
    p.demb = (const float*)d_in[5];
    p.traitW = (const float*)d_in[6];
    p.traitb = (const float*)d_in[7];
    p.intentW = (const float*)d_in[8];
    p.intentb = (const float*)d_in[9];
    p.cls = (const float*)d_in[10];
    p.bqkv = (const float*)d_in[12];
    p.bo = (const float*)d_in[14];
    p.ln1g = (const float*)d_in[15];
    p.ln1b = (const float*)d_in[16];
    p.b1 = (const float*)d_in[18];
    p.b2 = (const float*)d_in[20];
    p.ln2g = (const float*)d_in[21];
    p.ln2b = (const float*)d_in[22];
    p.outW = (const float*)d_in[23];
    p.outb = (const float*)d_in[24];
    p.olng = (const float*)d_in[25];
    p.olnb = (const float*)d_in[26];
    p.Wqkv = ws;                 // 36864
    p.Wo = ws + 36864;           // 12288
    p.W1 = ws + 49152;           // 98304
    p.W2 = ws + 147456;          // 98304
    p.tokpos = (const float*)(ws + TOKPOS_OFF);
    p.out = (float*)d_out;

    hipLaunchKernelGGL(fused_tfm_kernel, dim3(4096 / G), dim3(256), 0, stream, p);
}